// Round 6
// baseline (111.400 us; speedup 1.0000x reference)
//
#include <hip/hip_runtime.h>
#include <hip/hip_bf16.h>

typedef __hip_bfloat16 bf16;
typedef __attribute__((ext_vector_type(8))) short short8;
typedef __attribute__((ext_vector_type(4))) float f32x4;
typedef __attribute__((ext_vector_type(16))) float f32x16;

// exp2-domain Q scale: log2(e) / sqrt(512)  (reference divides energies by sqrt(E))
static constexpr float QSCALE = 1.4426950408889634f / 22.627416997969522f;

__device__ __forceinline__ void gload_lds16(const void* g, void* l) {
  __builtin_amdgcn_global_load_lds((const __attribute__((address_space(1))) unsigned*)(g),
                                   (__attribute__((address_space(3))) unsigned*)(l), 16, 0, 0);
}

// one v_cvt_pk_bf16_f32: {lo16=bf16(a), hi16=bf16(b)} (T12 recipe, m214v22)
__device__ __forceinline__ unsigned cvtpk(float a, float b) {
  unsigned r;
  asm("v_cvt_pk_bf16_f32 %0, %1, %2" : "=v"(r) : "v"(a), "v"(b));
  return r;
}

// ---------------- convert x (fp32 -> bf16), 8 elems/thread ----------------
__global__ __launch_bounds__(256) void cvt_x_kernel(const float* __restrict__ x,
                                                    bf16* __restrict__ xb, int n8) {
  for (int i = blockIdx.x * 256 + threadIdx.x; i < n8; i += gridDim.x * 256) {
    const float4* src = (const float4*)(x) + (size_t)i * 2;
    float4 a = src[0], b = src[1];
    union { short8 v; unsigned u[4]; } o;
    o.u[0] = cvtpk(a.x, a.y);
    o.u[1] = cvtpk(a.z, a.w);
    o.u[2] = cvtpk(b.x, b.y);
    o.u[3] = cvtpk(b.z, b.w);
    *(short8*)(xb + (size_t)i * 8) = o.v;
  }
}

// ------- transpose + convert weights: Wt[j'][k] = W[k][j], optional qkv-permute -------
// permute: j = h*192 + d*3 + s  ->  j' = s*512 + h*64 + d
__global__ __launch_bounds__(256) void transpose_cvt(const float* __restrict__ W,
                                                     bf16* __restrict__ Wt,
                                                     int Nout, int permute) {
  __shared__ float tile[64][65];
  const int j0 = blockIdx.x * 64, k0 = blockIdx.y * 64;
  const int tx = threadIdx.x & 63, ty = threadIdx.x >> 6;
  for (int r = ty; r < 64; r += 4)
    tile[r][tx] = W[(size_t)(k0 + r) * Nout + j0 + tx];
  __syncthreads();
  for (int r = ty; r < 64; r += 4) {
    int j = j0 + r;
    int jp = j;
    if (permute) {
      int h = j / 192, rr = j % 192, d = rr / 3, s = rr % 3;
      jp = s * 512 + h * 64 + d;
    }
    Wt[(size_t)jp * 512 + k0 + tx] = __float2bfloat16(tile[tx][r]);
  }
}

// ---------------- 128x128 bf16 GEMM (m97 structure), K=512, BK=32 ----------------
template <int MODE>
__global__ __launch_bounds__(256) void gemm_bt(const bf16* __restrict__ A,
                                               const bf16* __restrict__ Bt,
                                               const float* __restrict__ bias,
                                               bf16* __restrict__ Qb, bf16* __restrict__ Kb,
                                               bf16* __restrict__ Vt,
                                               float* __restrict__ Cout) {
  __shared__ short Alds[128 * 32];
  __shared__ short Blds[128 * 32];
  const int t = threadIdx.x;
  const int w = t >> 6;
  const int wr = w >> 1, wc = w & 1;
  const int lr = t & 15;
  const int lq = (t >> 4) & 3;
  const int bm = blockIdx.x, bn = blockIdx.y;

  f32x4 acc[4][4];
#pragma unroll
  for (int m = 0; m < 4; ++m)
#pragma unroll
    for (int n = 0; n < 4; ++n)
#pragma unroll
      for (int j = 0; j < 4; ++j) acc[m][n][j] = 0.f;

  for (int kt = 0; kt < 16; ++kt) {
#pragma unroll
    for (int i = 0; i < 2; ++i) {
      const int c = i * 256 + t;
      gload_lds16(A + (size_t)(bm * 128 + (c >> 2)) * 512 + kt * 32 + (c & 3) * 8,
                  &Alds[(i * 256 + w * 64) * 8]);
      gload_lds16(Bt + (size_t)(bn * 128 + (c >> 2)) * 512 + kt * 32 + (c & 3) * 8,
                  &Blds[(i * 256 + w * 64) * 8]);
    }
    __syncthreads();
    short8 af[4], bfr[4];
#pragma unroll
    for (int m = 0; m < 4; ++m)
      af[m] = *(const short8*)&Alds[(wr * 64 + m * 16 + lr) * 32 + lq * 8];
#pragma unroll
    for (int n = 0; n < 4; ++n)
      bfr[n] = *(const short8*)&Blds[(wc * 64 + n * 16 + lr) * 32 + lq * 8];
#pragma unroll
    for (int m = 0; m < 4; ++m)
#pragma unroll
      for (int n = 0; n < 4; ++n)
        acc[m][n] = __builtin_amdgcn_mfma_f32_16x16x32_bf16(af[m], bfr[n], acc[m][n], 0, 0, 0);
    __syncthreads();
  }

#pragma unroll
  for (int m = 0; m < 4; ++m) {
#pragma unroll
    for (int n = 0; n < 4; ++n) {
      const int col = bn * 128 + wc * 64 + n * 16 + lr;
#pragma unroll
      for (int j = 0; j < 4; ++j) {
        const int row = bm * 128 + wr * 64 + m * 16 + lq * 4 + j;
        float v = acc[m][n][j];
        if (MODE == 0) {
          const int s = col >> 9, h = (col >> 6) & 7, d = col & 63;
          v += bias[h * 192 + d * 3 + s];
          const int hd = col & 511;
          if (s == 0)
            Qb[(size_t)row * 512 + hd] = __float2bfloat16(v * QSCALE);
          else if (s == 1)
            Kb[(size_t)row * 512 + hd] = __float2bfloat16(v);
          else
            Vt[((size_t)((row >> 11) * 8 + h) * 64 + d) * 2048 + (row & 2047)] =
                __float2bfloat16(v);
        } else {
          v += bias[col];
          Cout[(size_t)row * 512 + col] = v;
        }
      }
    }
  }
}

// -------- flash attention fwd: 4 waves/block, split-K pairs, in-LDS merge --------
// Q,K: [8192][512] bf16 (col = h*64+d), Q pre-scaled by QSCALE. Vt: [bh][64][2048] bf16.
// O: [8192][512] bf16. Grid 512 (16 q-tiles x 32 bh; bh=bid&31 -> XCD-local K/V).
// Block = 256 thr = 4 waves covering 128 q-rows: waves {0,1} q[0,64), {2,3} q[64,128).
// Within a pair, wave (w&1)=0 does keys [0,1024), (w&1)=1 keys [1024,2048) -> 2048
// waves total = 2 waves/SIMD (the round-5 1-wave/SIMD latency wall). No max-shift
// (logits O(1)) => partial (O, sum-p) merge is an exact register-wise add, done in
// LDS at the end (rotate-swizzled, conflict-free).
__global__ __launch_bounds__(256) void attn_fwd(const bf16* __restrict__ Q,
                                                const bf16* __restrict__ K,
                                                const bf16* __restrict__ Vt,
                                                bf16* __restrict__ O) {
  // [half][row 64][8 chunks of 16B], source-pre-swizzled: slot (r,cc) holds chunk cc^(r&7)
  __shared__ short Klds[2][2][64 * 64];  // [dbuf][keyhalf][kv][d]   32 KB
  __shared__ short Vlds[2][2][64 * 64];  // [dbuf][keyhalf][d][kv]   32 KB
  const int t = threadIdx.x;
  const int w = t >> 6;
  const int half = w & 1;    // key-range half
  const int pair = w >> 1;   // q-subtile
  const int l = t & 63;
  const int lo = l & 31;
  const int hi = l >> 5;
  const int bid = blockIdx.x;
  const int bh = bid & 31, qt = bid >> 5;
  const int b = bh >> 3, h = bh & 7;
  const int qgA = qt * 128 + pair * 64 + lo;  // q-group A rows; B = A + 32

  const bf16* Kb = K + (size_t)b * 2048 * 512 + h * 64;
  const bf16* Vb = Vt + (size_t)bh * 64 * 2048;
  const int kb0 = half * 1024;  // this wave's key-range base

  // Q fragments (B-operand of QK^T): lane -> Q[q][d = kk*16 + hi*8 + 0..7]
  const bf16* qptrA = Q + ((size_t)b * 2048 + qgA) * 512 + h * 64 + hi * 8;
  short8 qfA[4], qfB[4];
#pragma unroll
  for (int kk = 0; kk < 4; ++kk) {
    qfA[kk] = *(const short8*)(qptrA + kk * 16);
    qfB[kk] = *(const short8*)(qptrA + 32 * 512 + kk * 16);
  }

  // persistent zero vector: C-operand of first QK^T MFMA (kills 32 v_mov per QK)
  f32x16 zv;
#pragma unroll
  for (int r = 0; r < 16; ++r) zv[r] = 0.f;

  f32x16 accA0, accA1, accB0, accB1;  // O^T partials: [d = crow(r,hi) + 32*dt][q]
#pragma unroll
  for (int r = 0; r < 16; ++r) { accA0[r] = 0.f; accA1[r] = 0.f; accB0[r] = 0.f; accB1[r] = 0.f; }
  float lsA = 0.f, lsB = 0.f;  // partial softmax denominators

  // staging: 4 tiles (K,V × keyhalf) × 512 chunks of 16B; 256 threads -> 8 chunks each.
#define STAGE(BUF, KV0)                                                               \
  do {                                                                                \
    _Pragma("unroll") for (int hf = 0; hf < 2; ++hf) {                                \
      _Pragma("unroll") for (int i = 0; i < 2; ++i) {                                 \
        const int c = i * 256 + t, r = c >> 3, g = (c & 7) ^ (r & 7);                 \
        gload_lds16(Kb + (size_t)(hf * 1024 + (KV0) + r) * 512 + g * 8,               \
                    &Klds[BUF][hf][(i * 256 + w * 64) * 8]);                          \
      }                                                                               \
      _Pragma("unroll") for (int i = 0; i < 2; ++i) {                                 \
        const int c = i * 256 + t, r = c >> 3, g = (c & 7) ^ (r & 7);                 \
        gload_lds16(Vb + (size_t)r * 2048 + hf * 1024 + (KV0) + g * 8,                \
                    &Vlds[BUF][hf][(i * 256 + w * 64) * 8]);                          \
      }                                                                               \
    }                                                                                 \
  } while (0)

  STAGE(0, 0);
  __syncthreads();

#pragma unroll 2
  for (int it = 0; it < 16; ++it) {
    const int buf = it & 1;
    if (it + 1 < 16) STAGE(buf ^ 1, (it + 1) * 64);

    const char* kl = (const char*)&Klds[buf][half][0];
    const char* vl = (const char*)&Vlds[buf][half][0];

#pragma unroll
    for (int sh = 0; sh < 2; ++sh) {  // 32-key sub-step: keys kb0 + it*64 + sh*32 + 0..31
      // K fragments: row sh*32+lo, chunk ((kk<<1)|hi)^(lo&7)
      short8 kf[4];
#pragma unroll
      for (int kk = 0; kk < 4; ++kk)
        kf[kk] = *(const short8*)(kl + ((sh * 32 + lo) << 7) +
                                  ((((kk << 1) | hi) ^ (lo & 7)) << 4));

      // S^T = mfma(K, Q) for both q-groups; lane holds S[q=lo][k=crow(r,hi)]
      f32x16 sA, sB;
      __builtin_amdgcn_s_setprio(1);
#pragma unroll
      for (int kk = 0; kk < 4; ++kk) {
        sA = __builtin_amdgcn_mfma_f32_32x32x16_bf16(kf[kk], qfA[kk], kk ? sA : zv, 0, 0, 0);
        sB = __builtin_amdgcn_mfma_f32_32x32x16_bf16(kf[kk], qfB[kk], kk ? sB : zv, 0, 0, 0);
      }
      __builtin_amdgcn_s_setprio(0);

      // V^T fragments for this key-half (independent of softmax)
      short8 vf[2][2];
#pragma unroll
      for (int dt = 0; dt < 2; ++dt)
#pragma unroll
        for (int j = 0; j < 2; ++j)
          vf[dt][j] = *(const short8*)(vl + ((dt * 32 + lo) << 7) +
                                       (((((sh * 2 + j) << 1) | hi) ^ (lo & 7)) << 4));

      // softmax numerator p = exp2(s) (scale folded into Q); accumulate denominators
      float tA = 0.f, tB = 0.f;
#pragma unroll
      for (int r = 0; r < 16; ++r) { sA[r] = __builtin_amdgcn_exp2f(sA[r]); tA += sA[r]; }
#pragma unroll
      for (int r = 0; r < 16; ++r) { sB[r] = __builtin_amdgcn_exp2f(sB[r]); tB += sB[r]; }
      lsA += tA;
      lsB += tB;

      // redistribute P into P^T B-operand frags: cvt_pk pairs + permlane32_swap
      short8 pbA[2], pbB[2];
#pragma unroll
      for (int g = 0; g < 2; ++g) {
        {
          unsigned a0 = cvtpk(sA[8 * g + 0], sA[8 * g + 1]);
          unsigned a1 = cvtpk(sA[8 * g + 2], sA[8 * g + 3]);
          unsigned b0 = cvtpk(sA[8 * g + 4], sA[8 * g + 5]);
          unsigned b1 = cvtpk(sA[8 * g + 6], sA[8 * g + 7]);
          asm("v_permlane32_swap_b32 %0, %1" : "+v"(a0), "+v"(b0));
          asm("v_permlane32_swap_b32 %0, %1" : "+v"(a1), "+v"(b1));
          union { unsigned u[4]; short8 v; } pu;
          pu.u[0] = a0; pu.u[1] = a1; pu.u[2] = b0; pu.u[3] = b1;
          pbA[g] = pu.v;
        }
        {
          unsigned a0 = cvtpk(sB[8 * g + 0], sB[8 * g + 1]);
          unsigned a1 = cvtpk(sB[8 * g + 2], sB[8 * g + 3]);
          unsigned b0 = cvtpk(sB[8 * g + 4], sB[8 * g + 5]);
          unsigned b1 = cvtpk(sB[8 * g + 6], sB[8 * g + 7]);
          asm("v_permlane32_swap_b32 %0, %1" : "+v"(a0), "+v"(b0));
          asm("v_permlane32_swap_b32 %0, %1" : "+v"(a1), "+v"(b1));
          union { unsigned u[4]; short8 v; } pu;
          pu.u[0] = a0; pu.u[1] = a1; pu.u[2] = b0; pu.u[3] = b1;
          pbB[g] = pu.v;
        }
      }

      // O^T += V^T * P^T (both q-groups share vf)
      __builtin_amdgcn_s_setprio(1);
#pragma unroll
      for (int j = 0; j < 2; ++j) {
        accA0 = __builtin_amdgcn_mfma_f32_32x32x16_bf16(vf[0][j], pbA[j], accA0, 0, 0, 0);
        accA1 = __builtin_amdgcn_mfma_f32_32x32x16_bf16(vf[1][j], pbA[j], accA1, 0, 0, 0);
        accB0 = __builtin_amdgcn_mfma_f32_32x32x16_bf16(vf[0][j], pbB[j], accB0, 0, 0, 0);
        accB1 = __builtin_amdgcn_mfma_f32_32x32x16_bf16(vf[1][j], pbB[j], accB1, 0, 0, 0);
      }
      __builtin_amdgcn_s_setprio(0);
    }

    __syncthreads();  // drains vmcnt (next tile staged) + protects buffer reuse
  }
#undef STAGE

  // -------- split-K merge: wave (half=1) hands partials to wave (half=0) via LDS --------
  lsA += __shfl_xor(lsA, 32);
  lsB += __shfl_xor(lsB, 32);

  float* mrg = (float*)&Klds[0][0][0];  // 32 KB: two pairs x 16 KB (rotate-swizzled)
  float* dnm = (float*)&Vlds[0][0][0];  // denominators: 2 pairs x 128 floats
  if (half) {
    float* base = mrg + pair * 4096;
#pragma unroll
    for (int r = 0; r < 16; ++r) {
      base[l * 64 + ((r + l) & 63)] = accA0[r];
      base[l * 64 + ((16 + r + l) & 63)] = accA1[r];
      base[l * 64 + ((32 + r + l) & 63)] = accB0[r];
      base[l * 64 + ((48 + r + l) & 63)] = accB1[r];
    }
    dnm[pair * 128 + l * 2] = lsA;
    dnm[pair * 128 + l * 2 + 1] = lsB;
  }
  __syncthreads();
  if (!half) {
    float* base = mrg + pair * 4096;
#pragma unroll
    for (int r = 0; r < 16; ++r) {
      accA0[r] += base[l * 64 + ((r + l) & 63)];
      accA1[r] += base[l * 64 + ((16 + r + l) & 63)];
      accB0[r] += base[l * 64 + ((32 + r + l) & 63)];
      accB1[r] += base[l * 64 + ((48 + r + l) & 63)];
    }
    lsA += dnm[pair * 128 + l * 2];
    lsB += dnm[pair * 128 + l * 2 + 1];
    const float rlA = 1.0f / lsA;
    const float rlB = 1.0f / lsB;
    bf16* opA = O + ((size_t)b * 2048 + qgA) * 512 + h * 64;
    bf16* opB = opA + 32 * 512;
#pragma unroll
    for (int r = 0; r < 16; ++r) {
      const int d = (r & 3) + 8 * (r >> 2) + 4 * hi;
      opA[d] = __float2bfloat16(accA0[r] * rlA);
      opA[32 + d] = __float2bfloat16(accA1[r] * rlA);
      opB[d] = __float2bfloat16(accB0[r] * rlB);
      opB[32 + d] = __float2bfloat16(accB1[r] * rlB);
    }
  }
}

// ---------------- launch ----------------
extern "C" void kernel_launch(void* const* d_in, const int* in_sizes, int n_in,
                              void* d_out, int out_size, void* d_ws, size_t ws_size,
                              hipStream_t stream) {
  const float* x = (const float*)d_in[0];      // [4,2048,512]
  const float* Wqkv = (const float*)d_in[1];   // [512,1536]
  const float* bqkv = (const float*)d_in[2];   // [1536]
  const float* Wproj = (const float*)d_in[3];  // [512,512]
  const float* bproj = (const float*)d_in[4];  // [512]
  float* out = (float*)d_out;                  // [4,2048,512] fp32

  char* ws = (char*)d_ws;
  bf16* xb = (bf16*)ws;                       // 8192*512
  bf16* Wqkvt = xb + (size_t)8192 * 512;      // 1536*512
  bf16* Wprojt = Wqkvt + (size_t)1536 * 512;  // 512*512
  bf16* Qb = Wprojt + (size_t)512 * 512;      // 8192*512
  bf16* Kb = Qb + (size_t)8192 * 512;         // 8192*512
  bf16* Vt = Kb + (size_t)8192 * 512;         // 32*64*2048
  bf16* Ob = xb;                              // alias: xb dead after gemm_bt<0>

  cvt_x_kernel<<<2048, 256, 0, stream>>>(x, xb, 8192 * 512 / 8);
  transpose_cvt<<<dim3(24, 8), 256, 0, stream>>>(Wqkv, Wqkvt, 1536, 1);
  transpose_cvt<<<dim3(8, 8), 256, 0, stream>>>(Wproj, Wprojt, 512, 0);
  gemm_bt<0><<<dim3(64, 12), 256, 0, stream>>>(xb, Wqkvt, bqkv, Qb, Kb, Vt, nullptr);
  attn_fwd<<<512, 256, 0, stream>>>(Qb, Kb, Vt, Ob);
  gemm_bt<1><<<dim3(64, 4), 256, 0, stream>>>(Ob, Wprojt, bproj, nullptr, nullptr, nullptr, out);
}

// Round 7
// 106.146 us; speedup vs baseline: 1.0495x; 1.0495x over previous
//
#include <hip/hip_runtime.h>
#include <hip/hip_bf16.h>

typedef __hip_bfloat16 bf16;
typedef __attribute__((ext_vector_type(8))) short short8;
typedef __attribute__((ext_vector_type(4))) float f32x4;
typedef __attribute__((ext_vector_type(16))) float f32x16;

// exp2-domain Q scale: log2(e) / sqrt(512)  (reference divides energies by sqrt(E))
static constexpr float QSCALE = 1.4426950408889634f / 22.627416997969522f;

__device__ __forceinline__ void gload_lds16(const void* g, void* l) {
  __builtin_amdgcn_global_load_lds((const __attribute__((address_space(1))) unsigned*)(g),
                                   (__attribute__((address_space(3))) unsigned*)(l), 16, 0, 0);
}

// one v_cvt_pk_bf16_f32: {lo16=bf16(a), hi16=bf16(b)} (T12 recipe, m214v22)
__device__ __forceinline__ unsigned cvtpk(float a, float b) {
  unsigned r;
  asm("v_cvt_pk_bf16_f32 %0, %1, %2" : "=v"(r) : "v"(a), "v"(b));
  return r;
}

// pack a 32-wide P row-slice (f32x16, this lane's 16 + partner's 16) into two
// B-operand bf16 fragments via cvt_pk + permlane32_swap (one swap fills 2 words)
__device__ __forceinline__ void packP(const f32x16& s, short8* pb) {
#pragma unroll
  for (int g = 0; g < 2; ++g) {
    unsigned a0 = cvtpk(s[8 * g + 0], s[8 * g + 1]);
    unsigned a1 = cvtpk(s[8 * g + 2], s[8 * g + 3]);
    unsigned b0 = cvtpk(s[8 * g + 4], s[8 * g + 5]);
    unsigned b1 = cvtpk(s[8 * g + 6], s[8 * g + 7]);
    asm("v_permlane32_swap_b32 %0, %1" : "+v"(a0), "+v"(b0));
    asm("v_permlane32_swap_b32 %0, %1" : "+v"(a1), "+v"(b1));
    union { unsigned u[4]; short8 v; } pu;
    pu.u[0] = a0; pu.u[1] = a1; pu.u[2] = b0; pu.u[3] = b1;
    pb[g] = pu.v;
  }
}

// ---------------- convert x (fp32 -> bf16), 8 elems/thread ----------------
__global__ __launch_bounds__(256) void cvt_x_kernel(const float* __restrict__ x,
                                                    bf16* __restrict__ xb, int n8) {
  for (int i = blockIdx.x * 256 + threadIdx.x; i < n8; i += gridDim.x * 256) {
    const float4* src = (const float4*)(x) + (size_t)i * 2;
    float4 a = src[0], b = src[1];
    union { short8 v; unsigned u[4]; } o;
    o.u[0] = cvtpk(a.x, a.y);
    o.u[1] = cvtpk(a.z, a.w);
    o.u[2] = cvtpk(b.x, b.y);
    o.u[3] = cvtpk(b.z, b.w);
    *(short8*)(xb + (size_t)i * 8) = o.v;
  }
}

// ------- transpose + convert weights: Wt[j'][k] = W[k][j], optional qkv-permute -------
// permute: j = h*192 + d*3 + s  ->  j' = s*512 + h*64 + d
__global__ __launch_bounds__(256) void transpose_cvt(const float* __restrict__ W,
                                                     bf16* __restrict__ Wt,
                                                     int Nout, int permute) {
  __shared__ float tile[64][65];
  const int j0 = blockIdx.x * 64, k0 = blockIdx.y * 64;
  const int tx = threadIdx.x & 63, ty = threadIdx.x >> 6;
  for (int r = ty; r < 64; r += 4)
    tile[r][tx] = W[(size_t)(k0 + r) * Nout + j0 + tx];
  __syncthreads();
  for (int r = ty; r < 64; r += 4) {
    int j = j0 + r;
    int jp = j;
    if (permute) {
      int h = j / 192, rr = j % 192, d = rr / 3, s = rr % 3;
      jp = s * 512 + h * 64 + d;
    }
    Wt[(size_t)jp * 512 + k0 + tx] = __float2bfloat16(tile[tx][r]);
  }
}

// ---------------- 128x128 bf16 GEMM (m97 structure), K=512, BK=32 ----------------
template <int MODE>
__global__ __launch_bounds__(256) void gemm_bt(const bf16* __restrict__ A,
                                               const bf16* __restrict__ Bt,
                                               const float* __restrict__ bias,
                                               bf16* __restrict__ Qb, bf16* __restrict__ Kb,
                                               bf16* __restrict__ Vt,
                                               float* __restrict__ Cout) {
  __shared__ short Alds[128 * 32];
  __shared__ short Blds[128 * 32];
  const int t = threadIdx.x;
  const int w = t >> 6;
  const int wr = w >> 1, wc = w & 1;
  const int lr = t & 15;
  const int lq = (t >> 4) & 3;
  const int bm = blockIdx.x, bn = blockIdx.y;

  f32x4 acc[4][4];
#pragma unroll
  for (int m = 0; m < 4; ++m)
#pragma unroll
    for (int n = 0; n < 4; ++n)
#pragma unroll
      for (int j = 0; j < 4; ++j) acc[m][n][j] = 0.f;

  for (int kt = 0; kt < 16; ++kt) {
#pragma unroll
    for (int i = 0; i < 2; ++i) {
      const int c = i * 256 + t;
      gload_lds16(A + (size_t)(bm * 128 + (c >> 2)) * 512 + kt * 32 + (c & 3) * 8,
                  &Alds[(i * 256 + w * 64) * 8]);
      gload_lds16(Bt + (size_t)(bn * 128 + (c >> 2)) * 512 + kt * 32 + (c & 3) * 8,
                  &Blds[(i * 256 + w * 64) * 8]);
    }
    __syncthreads();
    short8 af[4], bfr[4];
#pragma unroll
    for (int m = 0; m < 4; ++m)
      af[m] = *(const short8*)&Alds[(wr * 64 + m * 16 + lr) * 32 + lq * 8];
#pragma unroll
    for (int n = 0; n < 4; ++n)
      bfr[n] = *(const short8*)&Blds[(wc * 64 + n * 16 + lr) * 32 + lq * 8];
#pragma unroll
    for (int m = 0; m < 4; ++m)
#pragma unroll
      for (int n = 0; n < 4; ++n)
        acc[m][n] = __builtin_amdgcn_mfma_f32_16x16x32_bf16(af[m], bfr[n], acc[m][n], 0, 0, 0);
    __syncthreads();
  }

#pragma unroll
  for (int m = 0; m < 4; ++m) {
#pragma unroll
    for (int n = 0; n < 4; ++n) {
      const int col = bn * 128 + wc * 64 + n * 16 + lr;
#pragma unroll
      for (int j = 0; j < 4; ++j) {
        const int row = bm * 128 + wr * 64 + m * 16 + lq * 4 + j;
        float v = acc[m][n][j];
        if (MODE == 0) {
          const int s = col >> 9, h = (col >> 6) & 7, d = col & 63;
          v += bias[h * 192 + d * 3 + s];
          const int hd = col & 511;
          if (s == 0)
            Qb[(size_t)row * 512 + hd] = __float2bfloat16(v * QSCALE);
          else if (s == 1)
            Kb[(size_t)row * 512 + hd] = __float2bfloat16(v);
          else
            Vt[((size_t)((row >> 11) * 8 + h) * 64 + d) * 2048 + (row & 2047)] =
                __float2bfloat16(v);
        } else {
          v += bias[col];
          Cout[(size_t)row * 512 + col] = v;
        }
      }
    }
  }
}

// ------- flash attention fwd: 64 q/wave, software-pipelined substeps, KVBLK=64 -------
// Q,K: [8192][512] bf16 (col = h*64+d), Q pre-scaled by QSCALE. Vt: [bh][64][2048] bf16.
// O: [8192][512] bf16. Grid 512 (16 q-tiles x 32 bh; bh=bid&31 -> XCD-local K/V).
// Block = 2 waves x 64 q-rows. Grid-limited to 1 wave/SIMD, so the win is ILP:
// issue BOTH 32-key QK MFMA clusters up front (MFMA doesn't block the wave), then
// softmax(0) runs on VALU while QK(1) occupies the matrix pipe, and softmax(1)
// overlaps PV(0). Row-sums via ones-MFMA (no dependent fadd chains). No max-shift
// (logits O(1): exp2 can't overflow fp32; normalization makes the shift redundant).
__global__ __launch_bounds__(128, 1) void attn_fwd(const bf16* __restrict__ Q,
                                                   const bf16* __restrict__ K,
                                                   const bf16* __restrict__ Vt,
                                                   bf16* __restrict__ O) {
  // [row 64][8 chunks of 16B], source-pre-swizzled: slot (r,cc) holds chunk cc^(r&7)
  __shared__ short Klds[2][64 * 64];  // [kv][d]   16 KB
  __shared__ short Vlds[2][64 * 64];  // [d][kv]   16 KB
  const int t = threadIdx.x;
  const int w = t >> 6;
  const int l = t & 63;
  const int lo = l & 31;
  const int hi = l >> 5;
  const int bid = blockIdx.x;
  const int bh = bid & 31, qt = bid >> 5;
  const int b = bh >> 3, h = bh & 7;
  const int qgA = qt * 128 + w * 64 + lo;  // q-group A rows; B = A + 32

  const bf16* Kb = K + (size_t)b * 2048 * 512 + h * 64;
  const bf16* Vb = Vt + (size_t)bh * 64 * 2048;

  // Q fragments (B-operand of QK^T): lane -> Q[q][d = kk*16 + hi*8 + 0..7]
  const bf16* qptrA = Q + ((size_t)b * 2048 + qgA) * 512 + h * 64 + hi * 8;
  short8 qfA[4], qfB[4];
#pragma unroll
  for (int kk = 0; kk < 4; ++kk) {
    qfA[kk] = *(const short8*)(qptrA + kk * 16);
    qfB[kk] = *(const short8*)(qptrA + 32 * 512 + kk * 16);
  }

  // all-ones bf16 A-operand for row-sum MFMA
  union { unsigned u[4]; short8 v; } ones;
#pragma unroll
  for (int j = 0; j < 4; ++j) ones.u[j] = 0x3F803F80u;

  // persistent zero vector: C-operand of first QK^T MFMA (kills 32 v_mov per QK)
  f32x16 zv;
#pragma unroll
  for (int r = 0; r < 16; ++r) zv[r] = 0.f;

  f32x16 accA0, accA1, accB0, accB1;  // O^T: [d = crow(r,hi) + 32*dt][q]
  f32x16 ssumA, ssumB;                // P row-sums (every reg = lsum for q=lo)
#pragma unroll
  for (int r = 0; r < 16; ++r) {
    accA0[r] = 0.f; accA1[r] = 0.f; accB0[r] = 0.f; accB1[r] = 0.f;
    ssumA[r] = 0.f; ssumB[r] = 0.f;
  }

  // staging: 512 chunks each of K,V per tile; 128 threads -> 4 chunks each per array.
#define STAGE(BUF, KV0)                                                              \
  do {                                                                               \
    _Pragma("unroll") for (int i = 0; i < 4; ++i) {                                  \
      const int c = i * 128 + t, r = c >> 3, g = (c & 7) ^ (r & 7);                  \
      gload_lds16(Kb + (size_t)((KV0) + r) * 512 + g * 8,                            \
                  &Klds[BUF][(i * 128 + w * 64) * 8]);                               \
    }                                                                                \
    _Pragma("unroll") for (int i = 0; i < 4; ++i) {                                  \
      const int c = i * 128 + t, r = c >> 3, g = (c & 7) ^ (r & 7);                  \
      gload_lds16(Vb + (size_t)r * 2048 + (KV0) + g * 8,                             \
                  &Vlds[BUF][(i * 128 + w * 64) * 8]);                               \
    }                                                                                \
  } while (0)

  STAGE(0, 0);
  __syncthreads();

#pragma unroll 2
  for (int it = 0; it < 32; ++it) {
    const int buf = it & 1;
    if (it + 1 < 32) STAGE(buf ^ 1, (it + 1) * 64);

    const char* kl = (const char*)&Klds[buf][0];
    const char* vl = (const char*)&Vlds[buf][0];

    // K fragments for BOTH 32-key substeps (rows lo and 32+lo)
    short8 kf0[4], kf1[4];
#pragma unroll
    for (int kk = 0; kk < 4; ++kk) {
      kf0[kk] = *(const short8*)(kl + (lo << 7) + ((((kk << 1) | hi) ^ (lo & 7)) << 4));
      kf1[kk] = *(const short8*)(kl + ((32 + lo) << 7) + ((((kk << 1) | hi) ^ (lo & 7)) << 4));
    }

    // Issue QK MFMAs for BOTH substeps back-to-back: the matrix pipe stays busy
    // (~32 x 8cy) while the VALU below does softmax(0).
    f32x16 sA0, sB0, sA1, sB1;
    __builtin_amdgcn_s_setprio(1);
#pragma unroll
    for (int kk = 0; kk < 4; ++kk) {
      sA0 = __builtin_amdgcn_mfma_f32_32x32x16_bf16(kf0[kk], qfA[kk], kk ? sA0 : zv, 0, 0, 0);
      sB0 = __builtin_amdgcn_mfma_f32_32x32x16_bf16(kf0[kk], qfB[kk], kk ? sB0 : zv, 0, 0, 0);
    }
#pragma unroll
    for (int kk = 0; kk < 4; ++kk) {
      sA1 = __builtin_amdgcn_mfma_f32_32x32x16_bf16(kf1[kk], qfA[kk], kk ? sA1 : zv, 0, 0, 0);
      sB1 = __builtin_amdgcn_mfma_f32_32x32x16_bf16(kf1[kk], qfB[kk], kk ? sB1 : zv, 0, 0, 0);
    }
    __builtin_amdgcn_s_setprio(0);

    // V^T fragments, substep 0 (ds latency hides under QK pipe time)
    short8 vf0[2][2];
#pragma unroll
    for (int dt = 0; dt < 2; ++dt)
#pragma unroll
      for (int j = 0; j < 2; ++j)
        vf0[dt][j] = *(const short8*)(vl + ((dt * 32 + lo) << 7) +
                                      ((((j << 1) | hi) ^ (lo & 7)) << 4));

    // ---- softmax(0) on VALU: overlaps QK(1) in the matrix pipe ----
#pragma unroll
    for (int r = 0; r < 16; ++r) sA0[r] = __builtin_amdgcn_exp2f(sA0[r]);
#pragma unroll
    for (int r = 0; r < 16; ++r) sB0[r] = __builtin_amdgcn_exp2f(sB0[r]);
    short8 pbA0[2], pbB0[2];
    packP(sA0, pbA0);
    packP(sB0, pbB0);

    // ---- PV(0) + row-sum MFMAs ----
    __builtin_amdgcn_s_setprio(1);
#pragma unroll
    for (int j = 0; j < 2; ++j) {
      accA0 = __builtin_amdgcn_mfma_f32_32x32x16_bf16(vf0[0][j], pbA0[j], accA0, 0, 0, 0);
      accA1 = __builtin_amdgcn_mfma_f32_32x32x16_bf16(vf0[1][j], pbA0[j], accA1, 0, 0, 0);
      accB0 = __builtin_amdgcn_mfma_f32_32x32x16_bf16(vf0[0][j], pbB0[j], accB0, 0, 0, 0);
      accB1 = __builtin_amdgcn_mfma_f32_32x32x16_bf16(vf0[1][j], pbB0[j], accB1, 0, 0, 0);
      ssumA = __builtin_amdgcn_mfma_f32_32x32x16_bf16(ones.v, pbA0[j], ssumA, 0, 0, 0);
      ssumB = __builtin_amdgcn_mfma_f32_32x32x16_bf16(ones.v, pbB0[j], ssumB, 0, 0, 0);
    }
    __builtin_amdgcn_s_setprio(0);

    // V^T fragments, substep 1
    short8 vf1[2][2];
#pragma unroll
    for (int dt = 0; dt < 2; ++dt)
#pragma unroll
      for (int j = 0; j < 2; ++j)
        vf1[dt][j] = *(const short8*)(vl + ((dt * 32 + lo) << 7) +
                                      (((((2 + j) << 1) | hi) ^ (lo & 7)) << 4));

    // ---- softmax(1) on VALU: overlaps PV(0) in the matrix pipe ----
#pragma unroll
    for (int r = 0; r < 16; ++r) sA1[r] = __builtin_amdgcn_exp2f(sA1[r]);
#pragma unroll
    for (int r = 0; r < 16; ++r) sB1[r] = __builtin_amdgcn_exp2f(sB1[r]);
    short8 pbA1[2], pbB1[2];
    packP(sA1, pbA1);
    packP(sB1, pbB1);

    // ---- PV(1) + row-sum MFMAs ----
    __builtin_amdgcn_s_setprio(1);
#pragma unroll
    for (int j = 0; j < 2; ++j) {
      accA0 = __builtin_amdgcn_mfma_f32_32x32x16_bf16(vf1[0][j], pbA1[j], accA0, 0, 0, 0);
      accA1 = __builtin_amdgcn_mfma_f32_32x32x16_bf16(vf1[1][j], pbA1[j], accA1, 0, 0, 0);
      accB0 = __builtin_amdgcn_mfma_f32_32x32x16_bf16(vf1[0][j], pbB1[j], accB0, 0, 0, 0);
      accB1 = __builtin_amdgcn_mfma_f32_32x32x16_bf16(vf1[1][j], pbB1[j], accB1, 0, 0, 0);
      ssumA = __builtin_amdgcn_mfma_f32_32x32x16_bf16(ones.v, pbA1[j], ssumA, 0, 0, 0);
      ssumB = __builtin_amdgcn_mfma_f32_32x32x16_bf16(ones.v, pbB1[j], ssumB, 0, 0, 0);
    }
    __builtin_amdgcn_s_setprio(0);

    __syncthreads();  // drains vmcnt (next tile staged) + protects buffer reuse
  }
#undef STAGE

  const float rlA = 1.0f / ssumA[0];
  const float rlB = 1.0f / ssumB[0];
  bf16* opA = O + ((size_t)b * 2048 + qgA) * 512 + h * 64;
  bf16* opB = opA + 32 * 512;
#pragma unroll
  for (int r = 0; r < 16; ++r) {
    const int d = (r & 3) + 8 * (r >> 2) + 4 * hi;
    opA[d] = __float2bfloat16(accA0[r] * rlA);
    opA[32 + d] = __float2bfloat16(accA1[r] * rlA);
    opB[d] = __float2bfloat16(accB0[r] * rlB);
    opB[32 + d] = __float2bfloat16(accB1[r] * rlB);
  }
}

// ---------------- launch ----------------
extern "C" void kernel_launch(void* const* d_in, const int* in_sizes, int n_in,
                              void* d_out, int out_size, void* d_ws, size_t ws_size,
                              hipStream_t stream) {
  const float* x = (const float*)d_in[0];      // [4,2048,512]
  const float* Wqkv = (const float*)d_in[1];   // [512,1536]
  const float* bqkv = (const float*)d_in[2];   // [1536]
  const float* Wproj = (const float*)d_in[3];  // [512,512]
  const float* bproj = (const float*)d_in[4];  // [512]
  float* out = (float*)d_out;                  // [4,2048,512] fp32

  char* ws = (char*)d_ws;
  bf16* xb = (bf16*)ws;                       // 8192*512
  bf16* Wqkvt = xb + (size_t)8192 * 512;      // 1536*512
  bf16* Wprojt = Wqkvt + (size_t)1536 * 512;  // 512*512
  bf16* Qb = Wprojt + (size_t)512 * 512;      // 8192*512
  bf16* Kb = Qb + (size_t)8192 * 512;         // 8192*512
  bf16* Vt = Kb + (size_t)8192 * 512;         // 32*64*2048
  bf16* Ob = xb;                              // alias: xb dead after gemm_bt<0>

  cvt_x_kernel<<<2048, 256, 0, stream>>>(x, xb, 8192 * 512 / 8);
  transpose_cvt<<<dim3(24, 8), 256, 0, stream>>>(Wqkv, Wqkvt, 1536, 1);
  transpose_cvt<<<dim3(8, 8), 256, 0, stream>>>(Wproj, Wprojt, 512, 0);
  gemm_bt<0><<<dim3(64, 12), 256, 0, stream>>>(xb, Wqkvt, bqkv, Qb, Kb, Vt, nullptr);
  attn_fwd<<<512, 128, 0, stream>>>(Qb, Kb, Vt, Ob);
  gemm_bt<1><<<dim3(64, 4), 256, 0, stream>>>(Ob, Wprojt, bproj, nullptr, nullptr, nullptr, out);
}

// Round 8
// 103.577 us; speedup vs baseline: 1.0755x; 1.0248x over previous
//
#include <hip/hip_runtime.h>
#include <hip/hip_bf16.h>

typedef __hip_bfloat16 bf16;
typedef __attribute__((ext_vector_type(8))) short short8;
typedef __attribute__((ext_vector_type(4))) float f32x4;
typedef __attribute__((ext_vector_type(16))) float f32x16;

// exp2-domain Q scale: log2(e) / sqrt(512)  (reference divides energies by sqrt(E))
static constexpr float QSCALE = 1.4426950408889634f / 22.627416997969522f;

__device__ __forceinline__ void gload_lds16(const void* g, void* l) {
  __builtin_amdgcn_global_load_lds((const __attribute__((address_space(1))) unsigned*)(g),
                                   (__attribute__((address_space(3))) unsigned*)(l), 16, 0, 0);
}

// one v_cvt_pk_bf16_f32: {lo16=bf16(a), hi16=bf16(b)} (T12 recipe, m214v22)
__device__ __forceinline__ unsigned cvtpk(float a, float b) {
  unsigned r;
  asm("v_cvt_pk_bf16_f32 %0, %1, %2" : "=v"(r) : "v"(a), "v"(b));
  return r;
}

// pack a 32-wide P row-slice (f32x16, this lane's 16 + partner's 16) into two
// B-operand bf16 fragments via cvt_pk + permlane32_swap (one swap fills 2 words)
__device__ __forceinline__ void packP(const f32x16& s, short8* pb) {
#pragma unroll
  for (int g = 0; g < 2; ++g) {
    unsigned a0 = cvtpk(s[8 * g + 0], s[8 * g + 1]);
    unsigned a1 = cvtpk(s[8 * g + 2], s[8 * g + 3]);
    unsigned b0 = cvtpk(s[8 * g + 4], s[8 * g + 5]);
    unsigned b1 = cvtpk(s[8 * g + 6], s[8 * g + 7]);
    asm("v_permlane32_swap_b32 %0, %1" : "+v"(a0), "+v"(b0));
    asm("v_permlane32_swap_b32 %0, %1" : "+v"(a1), "+v"(b1));
    union { unsigned u[4]; short8 v; } pu;
    pu.u[0] = a0; pu.u[1] = a1; pu.u[2] = b0; pu.u[3] = b1;
    pb[g] = pu.v;
  }
}

// ---------------- convert x (fp32 -> bf16), 8 elems/thread ----------------
__global__ __launch_bounds__(256) void cvt_x_kernel(const float* __restrict__ x,
                                                    bf16* __restrict__ xb, int n8) {
  for (int i = blockIdx.x * 256 + threadIdx.x; i < n8; i += gridDim.x * 256) {
    const float4* src = (const float4*)(x) + (size_t)i * 2;
    float4 a = src[0], b = src[1];
    union { short8 v; unsigned u[4]; } o;
    o.u[0] = cvtpk(a.x, a.y);
    o.u[1] = cvtpk(a.z, a.w);
    o.u[2] = cvtpk(b.x, b.y);
    o.u[3] = cvtpk(b.z, b.w);
    *(short8*)(xb + (size_t)i * 8) = o.v;
  }
}

// ------- transpose + convert weights: Wt[j'][k] = W[k][j], optional qkv-permute -------
// permute: j = h*192 + d*3 + s  ->  j' = s*512 + h*64 + d
__global__ __launch_bounds__(256) void transpose_cvt(const float* __restrict__ W,
                                                     bf16* __restrict__ Wt,
                                                     int Nout, int permute) {
  __shared__ float tile[64][65];
  const int j0 = blockIdx.x * 64, k0 = blockIdx.y * 64;
  const int tx = threadIdx.x & 63, ty = threadIdx.x >> 6;
  for (int r = ty; r < 64; r += 4)
    tile[r][tx] = W[(size_t)(k0 + r) * Nout + j0 + tx];
  __syncthreads();
  for (int r = ty; r < 64; r += 4) {
    int j = j0 + r;
    int jp = j;
    if (permute) {
      int h = j / 192, rr = j % 192, d = rr / 3, s = rr % 3;
      jp = s * 512 + h * 64 + d;
    }
    Wt[(size_t)jp * 512 + k0 + tx] = __float2bfloat16(tile[tx][r]);
  }
}

// ---------------- 128x128 bf16 GEMM (m97 structure), K=512, BK=32 ----------------
template <int MODE>
__global__ __launch_bounds__(256) void gemm_bt(const bf16* __restrict__ A,
                                               const bf16* __restrict__ Bt,
                                               const float* __restrict__ bias,
                                               bf16* __restrict__ Qb, bf16* __restrict__ Kb,
                                               bf16* __restrict__ Vt,
                                               float* __restrict__ Cout) {
  __shared__ short Alds[128 * 32];
  __shared__ short Blds[128 * 32];
  const int t = threadIdx.x;
  const int w = t >> 6;
  const int wr = w >> 1, wc = w & 1;
  const int lr = t & 15;
  const int lq = (t >> 4) & 3;
  const int bm = blockIdx.x, bn = blockIdx.y;

  f32x4 acc[4][4];
#pragma unroll
  for (int m = 0; m < 4; ++m)
#pragma unroll
    for (int n = 0; n < 4; ++n)
#pragma unroll
      for (int j = 0; j < 4; ++j) acc[m][n][j] = 0.f;

  for (int kt = 0; kt < 16; ++kt) {
#pragma unroll
    for (int i = 0; i < 2; ++i) {
      const int c = i * 256 + t;
      gload_lds16(A + (size_t)(bm * 128 + (c >> 2)) * 512 + kt * 32 + (c & 3) * 8,
                  &Alds[(i * 256 + w * 64) * 8]);
      gload_lds16(Bt + (size_t)(bn * 128 + (c >> 2)) * 512 + kt * 32 + (c & 3) * 8,
                  &Blds[(i * 256 + w * 64) * 8]);
    }
    __syncthreads();
    short8 af[4], bfr[4];
#pragma unroll
    for (int m = 0; m < 4; ++m)
      af[m] = *(const short8*)&Alds[(wr * 64 + m * 16 + lr) * 32 + lq * 8];
#pragma unroll
    for (int n = 0; n < 4; ++n)
      bfr[n] = *(const short8*)&Blds[(wc * 64 + n * 16 + lr) * 32 + lq * 8];
#pragma unroll
    for (int m = 0; m < 4; ++m)
#pragma unroll
      for (int n = 0; n < 4; ++n)
        acc[m][n] = __builtin_amdgcn_mfma_f32_16x16x32_bf16(af[m], bfr[n], acc[m][n], 0, 0, 0);
    __syncthreads();
  }

#pragma unroll
  for (int m = 0; m < 4; ++m) {
#pragma unroll
    for (int n = 0; n < 4; ++n) {
      const int col = bn * 128 + wc * 64 + n * 16 + lr;
#pragma unroll
      for (int j = 0; j < 4; ++j) {
        const int row = bm * 128 + wr * 64 + m * 16 + lq * 4 + j;
        float v = acc[m][n][j];
        if (MODE == 0) {
          const int s = col >> 9, h = (col >> 6) & 7, d = col & 63;
          v += bias[h * 192 + d * 3 + s];
          const int hd = col & 511;
          if (s == 0)
            Qb[(size_t)row * 512 + hd] = __float2bfloat16(v * QSCALE);
          else if (s == 1)
            Kb[(size_t)row * 512 + hd] = __float2bfloat16(v);
          else
            Vt[((size_t)((row >> 11) * 8 + h) * 64 + d) * 2048 + (row & 2047)] =
                __float2bfloat16(v);
        } else {
          v += bias[col];
          Cout[(size_t)row * 512 + col] = v;
        }
      }
    }
  }
}

// ---- flash attention fwd: 4 waves/block, key-split wave pairs, SHARED staging ----
// Q,K: [8192][512] bf16 (col = h*64+d), Q pre-scaled by QSCALE. Vt: [bh][64][2048] bf16.
// O: [8192][512] bf16. Grid 512 (16 q-tiles x 32 bh; bh=bid&31 -> XCD-local K/V).
// Block = 256 thr = 4 waves over 128 q-rows. Wave (qw = w&1, kh = w>>1): q-subtile
// qw (64 q-rows), key-substep kh of EVERY 64-key tile (kh=0: keys [0,32) mod 64,
// kh=1: [32,64)). All 4 waves share ONE K/V staging stream (32 KB LDS -> 2 blocks/CU
// -> 2 waves/SIMD; R6's separate-stream version hit 64 KB and lost co-residency).
// No max-shift (logits O(1)) => partial (O, sum-p) merge is an exact add, done once
// at the end via LDS (rotate-indexed, conflict-free). launch_bounds(256,2) caps
// VGPR at 256 so 2 waves/EU genuinely fit.
__global__ __launch_bounds__(256, 2) void attn_fwd(const bf16* __restrict__ Q,
                                                   const bf16* __restrict__ K,
                                                   const bf16* __restrict__ Vt,
                                                   bf16* __restrict__ O) {
  // [row 64][8 chunks of 16B], source-pre-swizzled: slot (r,cc) holds chunk cc^(r&7)
  __shared__ short Klds[2][64 * 64];  // [kv][d]   16 KB
  __shared__ short Vlds[2][64 * 64];  // [d][kv]   16 KB
  __shared__ float dnm[2][128];       // partial softmax denominators
  const int t = threadIdx.x;
  const int w = t >> 6;
  const int qw = w & 1;   // q-subtile
  const int kh = w >> 1;  // key-substep
  const int l = t & 63;
  const int lo = l & 31;
  const int hi = l >> 5;
  const int bid = blockIdx.x;
  const int bh = bid & 31, qt = bid >> 5;
  const int b = bh >> 3, h = bh & 7;
  const int qgA = qt * 128 + qw * 64 + lo;  // q-group A rows; B = A + 32

  const bf16* Kb = K + (size_t)b * 2048 * 512 + h * 64;
  const bf16* Vb = Vt + (size_t)bh * 64 * 2048;

  // Q fragments (B-operand of QK^T): lane -> Q[q][d = kk*16 + hi*8 + 0..7]
  const bf16* qptrA = Q + ((size_t)b * 2048 + qgA) * 512 + h * 64 + hi * 8;
  short8 qfA[4], qfB[4];
#pragma unroll
  for (int kk = 0; kk < 4; ++kk) {
    qfA[kk] = *(const short8*)(qptrA + kk * 16);
    qfB[kk] = *(const short8*)(qptrA + 32 * 512 + kk * 16);
  }

  // all-ones bf16 A-operand for row-sum MFMA
  union { unsigned u[4]; short8 v; } ones;
#pragma unroll
  for (int j = 0; j < 4; ++j) ones.u[j] = 0x3F803F80u;

  // persistent zero vector: C-operand of first QK^T MFMA (kills 32 v_mov per QK)
  f32x16 zv;
#pragma unroll
  for (int r = 0; r < 16; ++r) zv[r] = 0.f;

  f32x16 accA0, accA1, accB0, accB1;  // partial O^T: [d = crow(r,hi) + 32*dt][q]
  f32x16 ssumA, ssumB;                // partial P row-sums (every reg = lsum for q=lo)
#pragma unroll
  for (int r = 0; r < 16; ++r) {
    accA0[r] = 0.f; accA1[r] = 0.f; accB0[r] = 0.f; accB1[r] = 0.f;
    ssumA[r] = 0.f; ssumB[r] = 0.f;
  }

  // staging: 512 chunks each of K,V per tile; 256 threads -> 2 chunks each per array.
#define STAGE(BUF, KV0)                                                              \
  do {                                                                               \
    _Pragma("unroll") for (int i = 0; i < 2; ++i) {                                  \
      const int c = i * 256 + t, r = c >> 3, g = (c & 7) ^ (r & 7);                  \
      gload_lds16(Kb + (size_t)((KV0) + r) * 512 + g * 8,                            \
                  &Klds[BUF][(i * 256 + w * 64) * 8]);                               \
    }                                                                                \
    _Pragma("unroll") for (int i = 0; i < 2; ++i) {                                  \
      const int c = i * 256 + t, r = c >> 3, g = (c & 7) ^ (r & 7);                  \
      gload_lds16(Vb + (size_t)r * 2048 + (KV0) + g * 8,                             \
                  &Vlds[BUF][(i * 256 + w * 64) * 8]);                               \
    }                                                                                \
  } while (0)

  STAGE(0, 0);
  __syncthreads();

#pragma unroll 2
  for (int it = 0; it < 32; ++it) {
    const int buf = it & 1;
    if (it + 1 < 32) STAGE(buf ^ 1, (it + 1) * 64);

    const char* kl = (const char*)&Klds[buf][0];
    const char* vl = (const char*)&Vlds[buf][0];

    // K fragments for THIS wave's substep (rows kh*32+lo); (row&7) == (lo&7)
    short8 kf[4];
#pragma unroll
    for (int kk = 0; kk < 4; ++kk)
      kf[kk] = *(const short8*)(kl + ((kh * 32 + lo) << 7) +
                                ((((kk << 1) | hi) ^ (lo & 7)) << 4));

    // S^T = mfma(K, Q) for both q-groups; lane holds S[q=lo][k=crow(r,hi)]
    f32x16 sA, sB;
    __builtin_amdgcn_s_setprio(1);
#pragma unroll
    for (int kk = 0; kk < 4; ++kk) {
      sA = __builtin_amdgcn_mfma_f32_32x32x16_bf16(kf[kk], qfA[kk], kk ? sA : zv, 0, 0, 0);
      sB = __builtin_amdgcn_mfma_f32_32x32x16_bf16(kf[kk], qfB[kk], kk ? sB : zv, 0, 0, 0);
    }
    __builtin_amdgcn_s_setprio(0);

    // V^T fragments for this substep (independent of softmax; hides under QK)
    short8 vf[2][2];
#pragma unroll
    for (int dt = 0; dt < 2; ++dt)
#pragma unroll
      for (int j = 0; j < 2; ++j)
        vf[dt][j] = *(const short8*)(vl + ((dt * 32 + lo) << 7) +
                                     (((((kh * 2 + j) << 1) | hi) ^ (lo & 7)) << 4));

    // softmax numerator p = exp2(s) (scale folded into Q), single v_exp_f32 each
#pragma unroll
    for (int r = 0; r < 16; ++r) sA[r] = __builtin_amdgcn_exp2f(sA[r]);
#pragma unroll
    for (int r = 0; r < 16; ++r) sB[r] = __builtin_amdgcn_exp2f(sB[r]);
    short8 pbA[2], pbB[2];
    packP(sA, pbA);
    packP(sB, pbB);

    // partial O^T += V^T * P^T;  partial ssum += 1 * P^T
    __builtin_amdgcn_s_setprio(1);
#pragma unroll
    for (int j = 0; j < 2; ++j) {
      accA0 = __builtin_amdgcn_mfma_f32_32x32x16_bf16(vf[0][j], pbA[j], accA0, 0, 0, 0);
      accA1 = __builtin_amdgcn_mfma_f32_32x32x16_bf16(vf[1][j], pbA[j], accA1, 0, 0, 0);
      accB0 = __builtin_amdgcn_mfma_f32_32x32x16_bf16(vf[0][j], pbB[j], accB0, 0, 0, 0);
      accB1 = __builtin_amdgcn_mfma_f32_32x32x16_bf16(vf[1][j], pbB[j], accB1, 0, 0, 0);
      ssumA = __builtin_amdgcn_mfma_f32_32x32x16_bf16(ones.v, pbA[j], ssumA, 0, 0, 0);
      ssumB = __builtin_amdgcn_mfma_f32_32x32x16_bf16(ones.v, pbB[j], ssumB, 0, 0, 0);
    }
    __builtin_amdgcn_s_setprio(0);

    __syncthreads();  // drains vmcnt (next tile staged) + protects buffer reuse
  }
#undef STAGE

  // ---- split-K merge: kh=1 waves hand partials to kh=0 waves via LDS (exact add) ----
  float lsA = ssumA[0], lsB = ssumB[0];
  float* base = qw ? (float*)&Vlds[0][0] : (float*)&Klds[0][0];  // 16 KB per q-subtile
  if (kh) {
#pragma unroll
    for (int r = 0; r < 16; ++r) {  // rotate-indexed: bank = (r+l)%32, conflict-free
      base[l * 64 + ((r + l) & 63)] = accA0[r];
      base[l * 64 + ((16 + r + l) & 63)] = accA1[r];
      base[l * 64 + ((32 + r + l) & 63)] = accB0[r];
      base[l * 64 + ((48 + r + l) & 63)] = accB1[r];
    }
    dnm[qw][l] = lsA;
    dnm[qw][64 + l] = lsB;
  }
  __syncthreads();
  if (!kh) {
#pragma unroll
    for (int r = 0; r < 16; ++r) {
      accA0[r] += base[l * 64 + ((r + l) & 63)];
      accA1[r] += base[l * 64 + ((16 + r + l) & 63)];
      accB0[r] += base[l * 64 + ((32 + r + l) & 63)];
      accB1[r] += base[l * 64 + ((48 + r + l) & 63)];
    }
    lsA += dnm[qw][l];
    lsB += dnm[qw][64 + l];
    const float rlA = 1.0f / lsA;
    const float rlB = 1.0f / lsB;
    bf16* opA = O + ((size_t)b * 2048 + qgA) * 512 + h * 64;
    bf16* opB = opA + 32 * 512;
#pragma unroll
    for (int r = 0; r < 16; ++r) {
      const int d = (r & 3) + 8 * (r >> 2) + 4 * hi;
      opA[d] = __float2bfloat16(accA0[r] * rlA);
      opA[32 + d] = __float2bfloat16(accA1[r] * rlA);
      opB[d] = __float2bfloat16(accB0[r] * rlB);
      opB[32 + d] = __float2bfloat16(accB1[r] * rlB);
    }
  }
}

// ---------------- launch ----------------
extern "C" void kernel_launch(void* const* d_in, const int* in_sizes, int n_in,
                              void* d_out, int out_size, void* d_ws, size_t ws_size,
                              hipStream_t stream) {
  const float* x = (const float*)d_in[0];      // [4,2048,512]
  const float* Wqkv = (const float*)d_in[1];   // [512,1536]
  const float* bqkv = (const float*)d_in[2];   // [1536]
  const float* Wproj = (const float*)d_in[3];  // [512,512]
  const float* bproj = (const float*)d_in[4];  // [512]
  float* out = (float*)d_out;                  // [4,2048,512] fp32

  char* ws = (char*)d_ws;
  bf16* xb = (bf16*)ws;                       // 8192*512
  bf16* Wqkvt = xb + (size_t)8192 * 512;      // 1536*512
  bf16* Wprojt = Wqkvt + (size_t)1536 * 512;  // 512*512
  bf16* Qb = Wprojt + (size_t)512 * 512;      // 8192*512
  bf16* Kb = Qb + (size_t)8192 * 512;         // 8192*512
  bf16* Vt = Kb + (size_t)8192 * 512;         // 32*64*2048
  bf16* Ob = xb;                              // alias: xb dead after gemm_bt<0>

  cvt_x_kernel<<<2048, 256, 0, stream>>>(x, xb, 8192 * 512 / 8);
  transpose_cvt<<<dim3(24, 8), 256, 0, stream>>>(Wqkv, Wqkvt, 1536, 1);
  transpose_cvt<<<dim3(8, 8), 256, 0, stream>>>(Wproj, Wprojt, 512, 0);
  gemm_bt<0><<<dim3(64, 12), 256, 0, stream>>>(xb, Wqkvt, bqkv, Qb, Kb, Vt, nullptr);
  attn_fwd<<<512, 256, 0, stream>>>(Qb, Kb, Vt, Ob);
  gemm_bt<1><<<dim3(64, 4), 256, 0, stream>>>(Ob, Wprojt, bproj, nullptr, nullptr, nullptr, out);
}

// Round 9
// 101.924 us; speedup vs baseline: 1.0930x; 1.0162x over previous
//
#include <hip/hip_runtime.h>
#include <hip/hip_bf16.h>

typedef __hip_bfloat16 bf16;
typedef __attribute__((ext_vector_type(8))) short short8;
typedef __attribute__((ext_vector_type(4))) float f32x4;
typedef __attribute__((ext_vector_type(16))) float f32x16;

// exp2-domain Q scale: log2(e) / sqrt(512)  (reference divides energies by sqrt(E))
static constexpr float QSCALE = 1.4426950408889634f / 22.627416997969522f;

__device__ __forceinline__ void gload_lds16(const void* g, void* l) {
  __builtin_amdgcn_global_load_lds((const __attribute__((address_space(1))) unsigned*)(g),
                                   (__attribute__((address_space(3))) unsigned*)(l), 16, 0, 0);
}

// one v_cvt_pk_bf16_f32: {lo16=bf16(a), hi16=bf16(b)} (T12 recipe, m214v22)
__device__ __forceinline__ unsigned cvtpk(float a, float b) {
  unsigned r;
  asm("v_cvt_pk_bf16_f32 %0, %1, %2" : "=v"(r) : "v"(a), "v"(b));
  return r;
}

// pack a 32-wide P row-slice (f32x16, this lane's 16 + partner's 16) into two
// B-operand bf16 fragments via cvt_pk + permlane32_swap (one swap fills 2 words)
__device__ __forceinline__ void packP(const f32x16& s, short8* pb) {
#pragma unroll
  for (int g = 0; g < 2; ++g) {
    unsigned a0 = cvtpk(s[8 * g + 0], s[8 * g + 1]);
    unsigned a1 = cvtpk(s[8 * g + 2], s[8 * g + 3]);
    unsigned b0 = cvtpk(s[8 * g + 4], s[8 * g + 5]);
    unsigned b1 = cvtpk(s[8 * g + 6], s[8 * g + 7]);
    asm("v_permlane32_swap_b32 %0, %1" : "+v"(a0), "+v"(b0));
    asm("v_permlane32_swap_b32 %0, %1" : "+v"(a1), "+v"(b1));
    union { unsigned u[4]; short8 v; } pu;
    pu.u[0] = a0; pu.u[1] = a1; pu.u[2] = b0; pu.u[3] = b1;
    pb[g] = pu.v;
  }
}

// ---------------- convert x (fp32 -> bf16), 8 elems/thread ----------------
__global__ __launch_bounds__(256) void cvt_x_kernel(const float* __restrict__ x,
                                                    bf16* __restrict__ xb, int n8) {
  for (int i = blockIdx.x * 256 + threadIdx.x; i < n8; i += gridDim.x * 256) {
    const float4* src = (const float4*)(x) + (size_t)i * 2;
    float4 a = src[0], b = src[1];
    union { short8 v; unsigned u[4]; } o;
    o.u[0] = cvtpk(a.x, a.y);
    o.u[1] = cvtpk(a.z, a.w);
    o.u[2] = cvtpk(b.x, b.y);
    o.u[3] = cvtpk(b.z, b.w);
    *(short8*)(xb + (size_t)i * 8) = o.v;
  }
}

// ------- transpose + convert weights: Wt[j'][k] = W[k][j], optional qkv-permute -------
// permute: j = h*192 + d*3 + s  ->  j' = s*512 + h*64 + d
__global__ __launch_bounds__(256) void transpose_cvt(const float* __restrict__ W,
                                                     bf16* __restrict__ Wt,
                                                     int Nout, int permute) {
  __shared__ float tile[64][65];
  const int j0 = blockIdx.x * 64, k0 = blockIdx.y * 64;
  const int tx = threadIdx.x & 63, ty = threadIdx.x >> 6;
  for (int r = ty; r < 64; r += 4)
    tile[r][tx] = W[(size_t)(k0 + r) * Nout + j0 + tx];
  __syncthreads();
  for (int r = ty; r < 64; r += 4) {
    int j = j0 + r;
    int jp = j;
    if (permute) {
      int h = j / 192, rr = j % 192, d = rr / 3, s = rr % 3;
      jp = s * 512 + h * 64 + d;
    }
    Wt[(size_t)jp * 512 + k0 + tx] = __float2bfloat16(tile[tx][r]);
  }
}

// ------------- QKV GEMM: 128x128 tile, BK=64, XOR-swizzled LDS (T2) -------------
// A [8192][512] bf16; Bt [1536][512] bf16 (out-col-major). Epilogue scatters to
// Q (pre-scaled), K, and V^T with the (h,d,s) de-interleave + bias.
__global__ __launch_bounds__(256, 3) void gemm_qkv(const bf16* __restrict__ A,
                                                   const bf16* __restrict__ Bt,
                                                   const float* __restrict__ bias,
                                                   bf16* __restrict__ Qb,
                                                   bf16* __restrict__ Kb,
                                                   bf16* __restrict__ Vt) {
  __shared__ short Alds[128 * 64];  // [row][8 chunks of 16B], chunk slot cc holds src chunk cc^(row&7)
  __shared__ short Blds[128 * 64];
  const int t = threadIdx.x;
  const int w = t >> 6;
  const int wr = w >> 1, wc = w & 1;
  const int lr = t & 15;
  const int lq = (t >> 4) & 3;
  const int bm = blockIdx.x, bn = blockIdx.y;

  f32x4 acc[4][4];
#pragma unroll
  for (int m = 0; m < 4; ++m)
#pragma unroll
    for (int n = 0; n < 4; ++n)
#pragma unroll
      for (int j = 0; j < 4; ++j) acc[m][n][j] = 0.f;

  for (int kt = 0; kt < 8; ++kt) {
    // stage 128x64 A and B tiles: 1024 chunks each, 4/thread, source-pre-swizzled
#pragma unroll
    for (int i = 0; i < 4; ++i) {
      const int c = i * 256 + t, r = c >> 3, g = (c & 7) ^ (r & 7);
      gload_lds16(A + (size_t)(bm * 128 + r) * 512 + kt * 64 + g * 8,
                  &Alds[(i * 256 + w * 64) * 8]);
    }
#pragma unroll
    for (int i = 0; i < 4; ++i) {
      const int c = i * 256 + t, r = c >> 3, g = (c & 7) ^ (r & 7);
      gload_lds16(Bt + (size_t)(bn * 128 + r) * 512 + kt * 64 + g * 8,
                  &Blds[(i * 256 + w * 64) * 8]);
    }
    __syncthreads();
#pragma unroll
    for (int kh2 = 0; kh2 < 2; ++kh2) {  // two K=32 halves of the BK=64 tile
      short8 af[4], bfr[4];
#pragma unroll
      for (int m = 0; m < 4; ++m)
        af[m] = *(const short8*)&Alds[(wr * 64 + m * 16 + lr) * 64 +
                                      ((((kh2 << 2) | lq) ^ (lr & 7)) << 3)];
#pragma unroll
      for (int n = 0; n < 4; ++n)
        bfr[n] = *(const short8*)&Blds[(wc * 64 + n * 16 + lr) * 64 +
                                       ((((kh2 << 2) | lq) ^ (lr & 7)) << 3)];
#pragma unroll
      for (int m = 0; m < 4; ++m)
#pragma unroll
        for (int n = 0; n < 4; ++n)
          acc[m][n] = __builtin_amdgcn_mfma_f32_16x16x32_bf16(af[m], bfr[n], acc[m][n], 0, 0, 0);
    }
    __syncthreads();
  }

#pragma unroll
  for (int m = 0; m < 4; ++m) {
#pragma unroll
    for (int n = 0; n < 4; ++n) {
      const int col = bn * 128 + wc * 64 + n * 16 + lr;
      const int s = col >> 9, h = (col >> 6) & 7, d = col & 63;
      const float bv = bias[h * 192 + d * 3 + s];
      const int hd = col & 511;
#pragma unroll
      for (int j = 0; j < 4; ++j) {
        const int row = bm * 128 + wr * 64 + m * 16 + lq * 4 + j;
        const float v = acc[m][n][j] + bv;
        if (s == 0)
          Qb[(size_t)row * 512 + hd] = __float2bfloat16(v * QSCALE);
        else if (s == 1)
          Kb[(size_t)row * 512 + hd] = __float2bfloat16(v);
        else
          Vt[((size_t)((row >> 11) * 8 + h) * 64 + d) * 2048 + (row & 2047)] =
              __float2bfloat16(v);
      }
    }
  }
}

// ------------- proj GEMM: 128x64 tile, BK=64, XOR-swizzled LDS -------------
// grid (64,8) = 512 blocks = 2 blocks/CU (fixes the 1-wave/SIMD latency wall).
__global__ __launch_bounds__(256, 2) void gemm_proj(const bf16* __restrict__ A,
                                                    const bf16* __restrict__ Bt,
                                                    const float* __restrict__ bias,
                                                    float* __restrict__ Cout) {
  __shared__ short Alds[128 * 64];  // 16 KB
  __shared__ short Blds[64 * 64];   // 8 KB
  const int t = threadIdx.x;
  const int w = t >> 6;
  const int wr = w >> 1, wc = w & 1;
  const int lr = t & 15;
  const int lq = (t >> 4) & 3;
  const int bm = blockIdx.x, bn = blockIdx.y;

  f32x4 acc[4][2];
#pragma unroll
  for (int m = 0; m < 4; ++m)
#pragma unroll
    for (int n = 0; n < 2; ++n)
#pragma unroll
      for (int j = 0; j < 4; ++j) acc[m][n][j] = 0.f;

  for (int kt = 0; kt < 8; ++kt) {
#pragma unroll
    for (int i = 0; i < 4; ++i) {
      const int c = i * 256 + t, r = c >> 3, g = (c & 7) ^ (r & 7);
      gload_lds16(A + (size_t)(bm * 128 + r) * 512 + kt * 64 + g * 8,
                  &Alds[(i * 256 + w * 64) * 8]);
    }
#pragma unroll
    for (int i = 0; i < 2; ++i) {
      const int c = i * 256 + t, r = c >> 3, g = (c & 7) ^ (r & 7);
      gload_lds16(Bt + (size_t)(bn * 64 + r) * 512 + kt * 64 + g * 8,
                  &Blds[(i * 256 + w * 64) * 8]);
    }
    __syncthreads();
#pragma unroll
    for (int kh2 = 0; kh2 < 2; ++kh2) {
      short8 af[4], bfr[2];
#pragma unroll
      for (int m = 0; m < 4; ++m)
        af[m] = *(const short8*)&Alds[(wr * 64 + m * 16 + lr) * 64 +
                                      ((((kh2 << 2) | lq) ^ (lr & 7)) << 3)];
#pragma unroll
      for (int n = 0; n < 2; ++n)
        bfr[n] = *(const short8*)&Blds[(wc * 32 + n * 16 + lr) * 64 +
                                       ((((kh2 << 2) | lq) ^ (lr & 7)) << 3)];
#pragma unroll
      for (int m = 0; m < 4; ++m)
#pragma unroll
        for (int n = 0; n < 2; ++n)
          acc[m][n] = __builtin_amdgcn_mfma_f32_16x16x32_bf16(af[m], bfr[n], acc[m][n], 0, 0, 0);
    }
    __syncthreads();
  }

#pragma unroll
  for (int m = 0; m < 4; ++m) {
#pragma unroll
    for (int n = 0; n < 2; ++n) {
      const int col = bn * 64 + wc * 32 + n * 16 + lr;
      const float bv = bias[col];
#pragma unroll
      for (int j = 0; j < 4; ++j) {
        const int row = bm * 128 + wr * 64 + m * 16 + lq * 4 + j;
        Cout[(size_t)row * 512 + col] = acc[m][n][j] + bv;
      }
    }
  }
}

// ---- flash attention fwd: 4 waves/block, key-split wave pairs, SHARED staging ----
// (unchanged from round 8: 2 waves/SIMD, exact split-K merge, no max-shift)
__global__ __launch_bounds__(256, 2) void attn_fwd(const bf16* __restrict__ Q,
                                                   const bf16* __restrict__ K,
                                                   const bf16* __restrict__ Vt,
                                                   bf16* __restrict__ O) {
  // [row 64][8 chunks of 16B], source-pre-swizzled: slot (r,cc) holds chunk cc^(r&7)
  __shared__ short Klds[2][64 * 64];  // [kv][d]   16 KB
  __shared__ short Vlds[2][64 * 64];  // [d][kv]   16 KB
  __shared__ float dnm[2][128];       // partial softmax denominators
  const int t = threadIdx.x;
  const int w = t >> 6;
  const int qw = w & 1;   // q-subtile
  const int kh = w >> 1;  // key-substep
  const int l = t & 63;
  const int lo = l & 31;
  const int hi = l >> 5;
  const int bid = blockIdx.x;
  const int bh = bid & 31, qt = bid >> 5;
  const int b = bh >> 3, h = bh & 7;
  const int qgA = qt * 128 + qw * 64 + lo;  // q-group A rows; B = A + 32

  const bf16* Kb = K + (size_t)b * 2048 * 512 + h * 64;
  const bf16* Vb = Vt + (size_t)bh * 64 * 2048;

  // Q fragments (B-operand of QK^T): lane -> Q[q][d = kk*16 + hi*8 + 0..7]
  const bf16* qptrA = Q + ((size_t)b * 2048 + qgA) * 512 + h * 64 + hi * 8;
  short8 qfA[4], qfB[4];
#pragma unroll
  for (int kk = 0; kk < 4; ++kk) {
    qfA[kk] = *(const short8*)(qptrA + kk * 16);
    qfB[kk] = *(const short8*)(qptrA + 32 * 512 + kk * 16);
  }

  // all-ones bf16 A-operand for row-sum MFMA
  union { unsigned u[4]; short8 v; } ones;
#pragma unroll
  for (int j = 0; j < 4; ++j) ones.u[j] = 0x3F803F80u;

  // persistent zero vector: C-operand of first QK^T MFMA (kills 32 v_mov per QK)
  f32x16 zv;
#pragma unroll
  for (int r = 0; r < 16; ++r) zv[r] = 0.f;

  f32x16 accA0, accA1, accB0, accB1;  // partial O^T: [d = crow(r,hi) + 32*dt][q]
  f32x16 ssumA, ssumB;                // partial P row-sums (every reg = lsum for q=lo)
#pragma unroll
  for (int r = 0; r < 16; ++r) {
    accA0[r] = 0.f; accA1[r] = 0.f; accB0[r] = 0.f; accB1[r] = 0.f;
    ssumA[r] = 0.f; ssumB[r] = 0.f;
  }

  // staging: 512 chunks each of K,V per tile; 256 threads -> 2 chunks each per array.
#define STAGE(BUF, KV0)                                                              \
  do {                                                                               \
    _Pragma("unroll") for (int i = 0; i < 2; ++i) {                                  \
      const int c = i * 256 + t, r = c >> 3, g = (c & 7) ^ (r & 7);                  \
      gload_lds16(Kb + (size_t)((KV0) + r) * 512 + g * 8,                            \
                  &Klds[BUF][(i * 256 + w * 64) * 8]);                               \
    }                                                                                \
    _Pragma("unroll") for (int i = 0; i < 2; ++i) {                                  \
      const int c = i * 256 + t, r = c >> 3, g = (c & 7) ^ (r & 7);                  \
      gload_lds16(Vb + (size_t)r * 2048 + (KV0) + g * 8,                             \
                  &Vlds[BUF][(i * 256 + w * 64) * 8]);                               \
    }                                                                                \
  } while (0)

  STAGE(0, 0);
  __syncthreads();

#pragma unroll 2
  for (int it = 0; it < 32; ++it) {
    const int buf = it & 1;
    if (it + 1 < 32) STAGE(buf ^ 1, (it + 1) * 64);

    const char* kl = (const char*)&Klds[buf][0];
    const char* vl = (const char*)&Vlds[buf][0];

    // K fragments for THIS wave's substep (rows kh*32+lo); (row&7) == (lo&7)
    short8 kf[4];
#pragma unroll
    for (int kk = 0; kk < 4; ++kk)
      kf[kk] = *(const short8*)(kl + ((kh * 32 + lo) << 7) +
                                ((((kk << 1) | hi) ^ (lo & 7)) << 4));

    // S^T = mfma(K, Q) for both q-groups; lane holds S[q=lo][k=crow(r,hi)]
    f32x16 sA, sB;
    __builtin_amdgcn_s_setprio(1);
#pragma unroll
    for (int kk = 0; kk < 4; ++kk) {
      sA = __builtin_amdgcn_mfma_f32_32x32x16_bf16(kf[kk], qfA[kk], kk ? sA : zv, 0, 0, 0);
      sB = __builtin_amdgcn_mfma_f32_32x32x16_bf16(kf[kk], qfB[kk], kk ? sB : zv, 0, 0, 0);
    }
    __builtin_amdgcn_s_setprio(0);

    // V^T fragments for this substep (independent of softmax; hides under QK)
    short8 vf[2][2];
#pragma unroll
    for (int dt = 0; dt < 2; ++dt)
#pragma unroll
      for (int j = 0; j < 2; ++j)
        vf[dt][j] = *(const short8*)(vl + ((dt * 32 + lo) << 7) +
                                     (((((kh * 2 + j) << 1) | hi) ^ (lo & 7)) << 4));

    // softmax numerator p = exp2(s) (scale folded into Q), single v_exp_f32 each
#pragma unroll
    for (int r = 0; r < 16; ++r) sA[r] = __builtin_amdgcn_exp2f(sA[r]);
#pragma unroll
    for (int r = 0; r < 16; ++r) sB[r] = __builtin_amdgcn_exp2f(sB[r]);
    short8 pbA[2], pbB[2];
    packP(sA, pbA);
    packP(sB, pbB);

    // partial O^T += V^T * P^T;  partial ssum += 1 * P^T
    __builtin_amdgcn_s_setprio(1);
#pragma unroll
    for (int j = 0; j < 2; ++j) {
      accA0 = __builtin_amdgcn_mfma_f32_32x32x16_bf16(vf[0][j], pbA[j], accA0, 0, 0, 0);
      accA1 = __builtin_amdgcn_mfma_f32_32x32x16_bf16(vf[1][j], pbA[j], accA1, 0, 0, 0);
      accB0 = __builtin_amdgcn_mfma_f32_32x32x16_bf16(vf[0][j], pbB[j], accB0, 0, 0, 0);
      accB1 = __builtin_amdgcn_mfma_f32_32x32x16_bf16(vf[1][j], pbB[j], accB1, 0, 0, 0);
      ssumA = __builtin_amdgcn_mfma_f32_32x32x16_bf16(ones.v, pbA[j], ssumA, 0, 0, 0);
      ssumB = __builtin_amdgcn_mfma_f32_32x32x16_bf16(ones.v, pbB[j], ssumB, 0, 0, 0);
    }
    __builtin_amdgcn_s_setprio(0);

    __syncthreads();  // drains vmcnt (next tile staged) + protects buffer reuse
  }
#undef STAGE

  // ---- split-K merge: kh=1 waves hand partials to kh=0 waves via LDS (exact add) ----
  float lsA = ssumA[0], lsB = ssumB[0];
  float* base = qw ? (float*)&Vlds[0][0] : (float*)&Klds[0][0];  // 16 KB per q-subtile
  if (kh) {
#pragma unroll
    for (int r = 0; r < 16; ++r) {  // rotate-indexed: bank = (r+l)%32, conflict-free
      base[l * 64 + ((r + l) & 63)] = accA0[r];
      base[l * 64 + ((16 + r + l) & 63)] = accA1[r];
      base[l * 64 + ((32 + r + l) & 63)] = accB0[r];
      base[l * 64 + ((48 + r + l) & 63)] = accB1[r];
    }
    dnm[qw][l] = lsA;
    dnm[qw][64 + l] = lsB;
  }
  __syncthreads();
  if (!kh) {
#pragma unroll
    for (int r = 0; r < 16; ++r) {
      accA0[r] += base[l * 64 + ((r + l) & 63)];
      accA1[r] += base[l * 64 + ((16 + r + l) & 63)];
      accB0[r] += base[l * 64 + ((32 + r + l) & 63)];
      accB1[r] += base[l * 64 + ((48 + r + l) & 63)];
    }
    lsA += dnm[qw][l];
    lsB += dnm[qw][64 + l];
    const float rlA = 1.0f / lsA;
    const float rlB = 1.0f / lsB;
    bf16* opA = O + ((size_t)b * 2048 + qgA) * 512 + h * 64;
    bf16* opB = opA + 32 * 512;
#pragma unroll
    for (int r = 0; r < 16; ++r) {
      const int d = (r & 3) + 8 * (r >> 2) + 4 * hi;
      opA[d] = __float2bfloat16(accA0[r] * rlA);
      opA[32 + d] = __float2bfloat16(accA1[r] * rlA);
      opB[d] = __float2bfloat16(accB0[r] * rlB);
      opB[32 + d] = __float2bfloat16(accB1[r] * rlB);
    }
  }
}

// ---------------- launch ----------------
extern "C" void kernel_launch(void* const* d_in, const int* in_sizes, int n_in,
                              void* d_out, int out_size, void* d_ws, size_t ws_size,
                              hipStream_t stream) {
  const float* x = (const float*)d_in[0];      // [4,2048,512]
  const float* Wqkv = (const float*)d_in[1];   // [512,1536]
  const float* bqkv = (const float*)d_in[2];   // [1536]
  const float* Wproj = (const float*)d_in[3];  // [512,512]
  const float* bproj = (const float*)d_in[4];  // [512]
  float* out = (float*)d_out;                  // [4,2048,512] fp32

  char* ws = (char*)d_ws;
  bf16* xb = (bf16*)ws;                       // 8192*512
  bf16* Wqkvt = xb + (size_t)8192 * 512;      // 1536*512
  bf16* Wprojt = Wqkvt + (size_t)1536 * 512;  // 512*512
  bf16* Qb = Wprojt + (size_t)512 * 512;      // 8192*512
  bf16* Kb = Qb + (size_t)8192 * 512;         // 8192*512
  bf16* Vt = Kb + (size_t)8192 * 512;         // 32*64*2048
  bf16* Ob = xb;                              // alias: xb dead after gemm_qkv

  cvt_x_kernel<<<2048, 256, 0, stream>>>(x, xb, 8192 * 512 / 8);
  transpose_cvt<<<dim3(24, 8), 256, 0, stream>>>(Wqkv, Wqkvt, 1536, 1);
  transpose_cvt<<<dim3(8, 8), 256, 0, stream>>>(Wproj, Wprojt, 512, 0);
  gemm_qkv<<<dim3(64, 12), 256, 0, stream>>>(xb, Wqkvt, bqkv, Qb, Kb, Vt);
  attn_fwd<<<512, 256, 0, stream>>>(Qb, Kb, Vt, Ob);
  gemm_proj<<<dim3(64, 8), 256, 0, stream>>>(Ob, Wprojt, bproj, out);
}

// Round 10
// 94.703 us; speedup vs baseline: 1.1763x; 1.0763x over previous
//
#include <hip/hip_runtime.h>
#include <hip/hip_bf16.h>

typedef __hip_bfloat16 bf16;
typedef __attribute__((ext_vector_type(8))) short short8;
typedef __attribute__((ext_vector_type(4))) float f32x4;
typedef __attribute__((ext_vector_type(16))) float f32x16;

// exp2-domain Q scale: log2(e) / sqrt(512)  (reference divides energies by sqrt(E))
static constexpr float QSCALE = 1.4426950408889634f / 22.627416997969522f;

__device__ __forceinline__ void gload_lds16(const void* g, void* l) {
  __builtin_amdgcn_global_load_lds((const __attribute__((address_space(1))) unsigned*)(g),
                                   (__attribute__((address_space(3))) unsigned*)(l), 16, 0, 0);
}

// one v_cvt_pk_bf16_f32: {lo16=bf16(a), hi16=bf16(b)} (T12 recipe, m214v22)
__device__ __forceinline__ unsigned cvtpk(float a, float b) {
  unsigned r;
  asm("v_cvt_pk_bf16_f32 %0, %1, %2" : "=v"(r) : "v"(a), "v"(b));
  return r;
}

// pack a 32-wide P row-slice (f32x16, this lane's 16 + partner's 16) into two
// B-operand bf16 fragments via cvt_pk + permlane32_swap (one swap fills 2 words)
__device__ __forceinline__ void packP(const f32x16& s, short8* pb) {
#pragma unroll
  for (int g = 0; g < 2; ++g) {
    unsigned a0 = cvtpk(s[8 * g + 0], s[8 * g + 1]);
    unsigned a1 = cvtpk(s[8 * g + 2], s[8 * g + 3]);
    unsigned b0 = cvtpk(s[8 * g + 4], s[8 * g + 5]);
    unsigned b1 = cvtpk(s[8 * g + 6], s[8 * g + 7]);
    asm("v_permlane32_swap_b32 %0, %1" : "+v"(a0), "+v"(b0));
    asm("v_permlane32_swap_b32 %0, %1" : "+v"(a1), "+v"(b1));
    union { unsigned u[4]; short8 v; } pu;
    pu.u[0] = a0; pu.u[1] = a1; pu.u[2] = b0; pu.u[3] = b1;
    pb[g] = pu.v;
  }
}

// ------ fused prep: cvt x->bf16 (blocks 0..2047), Wqkv transpose+permute (2048..2239),
// ------ Wproj transpose (2240..2303). Branch is block-uniform -> __syncthreads legal.
__global__ __launch_bounds__(256) void prep_kernel(const float* __restrict__ x,
                                                   bf16* __restrict__ xb,
                                                   const float* __restrict__ Wqkv,
                                                   bf16* __restrict__ Wqkvt,
                                                   const float* __restrict__ Wproj,
                                                   bf16* __restrict__ Wprojt) {
  __shared__ float tile[64][65];
  const int bid = blockIdx.x;
  if (bid < 2048) {
    // ---- cvt_x: 8 elems/thread, one pass ----
    const int i = bid * 256 + threadIdx.x;  // 0..524287 = 8192*512/8
    const float4* src = (const float4*)(x) + (size_t)i * 2;
    float4 a = src[0], b = src[1];
    union { short8 v; unsigned u[4]; } o;
    o.u[0] = cvtpk(a.x, a.y);
    o.u[1] = cvtpk(a.z, a.w);
    o.u[2] = cvtpk(b.x, b.y);
    o.u[3] = cvtpk(b.z, b.w);
    *(short8*)(xb + (size_t)i * 8) = o.v;
  } else {
    // ---- weight transpose+cvt: Wt[j'][k] = W[k][j] ----
    const float* W;
    bf16* Wt;
    int Nout, permute, j0, k0;
    if (bid < 2048 + 192) {
      const int tb = bid - 2048;  // 24 x 8 tiles
      W = Wqkv; Wt = Wqkvt; Nout = 1536; permute = 1;
      j0 = (tb % 24) * 64; k0 = (tb / 24) * 64;
    } else {
      const int tb = bid - 2240;  // 8 x 8 tiles
      W = Wproj; Wt = Wprojt; Nout = 512; permute = 0;
      j0 = (tb % 8) * 64; k0 = (tb / 8) * 64;
    }
    const int tx = threadIdx.x & 63, ty = threadIdx.x >> 6;
    for (int r = ty; r < 64; r += 4)
      tile[r][tx] = W[(size_t)(k0 + r) * Nout + j0 + tx];
    __syncthreads();
    for (int r = ty; r < 64; r += 4) {
      int j = j0 + r;
      int jp = j;
      if (permute) {
        int h = j / 192, rr = j % 192, d = rr / 3, s = rr % 3;
        jp = s * 512 + h * 64 + d;
      }
      Wt[(size_t)jp * 512 + k0 + tx] = __float2bfloat16(tile[tx][r]);
    }
  }
}

// ------------- QKV GEMM: 128x128 tile, BK=64, XOR-swizzled LDS (T2) -------------
// A [8192][512] bf16; Bt [1536][512] bf16 (out-col-major). Epilogue scatters to
// Q (pre-scaled), K, and V^T with the (h,d,s) de-interleave + bias.
__global__ __launch_bounds__(256, 3) void gemm_qkv(const bf16* __restrict__ A,
                                                   const bf16* __restrict__ Bt,
                                                   const float* __restrict__ bias,
                                                   bf16* __restrict__ Qb,
                                                   bf16* __restrict__ Kb,
                                                   bf16* __restrict__ Vt) {
  __shared__ short Alds[128 * 64];  // [row][8 chunks of 16B], chunk slot cc holds src chunk cc^(row&7)
  __shared__ short Blds[128 * 64];
  const int t = threadIdx.x;
  const int w = t >> 6;
  const int wr = w >> 1, wc = w & 1;
  const int lr = t & 15;
  const int lq = (t >> 4) & 3;
  const int bm = blockIdx.x, bn = blockIdx.y;

  f32x4 acc[4][4];
#pragma unroll
  for (int m = 0; m < 4; ++m)
#pragma unroll
    for (int n = 0; n < 4; ++n)
#pragma unroll
      for (int j = 0; j < 4; ++j) acc[m][n][j] = 0.f;

  for (int kt = 0; kt < 8; ++kt) {
    // stage 128x64 A and B tiles: 1024 chunks each, 4/thread, source-pre-swizzled
#pragma unroll
    for (int i = 0; i < 4; ++i) {
      const int c = i * 256 + t, r = c >> 3, g = (c & 7) ^ (r & 7);
      gload_lds16(A + (size_t)(bm * 128 + r) * 512 + kt * 64 + g * 8,
                  &Alds[(i * 256 + w * 64) * 8]);
    }
#pragma unroll
    for (int i = 0; i < 4; ++i) {
      const int c = i * 256 + t, r = c >> 3, g = (c & 7) ^ (r & 7);
      gload_lds16(Bt + (size_t)(bn * 128 + r) * 512 + kt * 64 + g * 8,
                  &Blds[(i * 256 + w * 64) * 8]);
    }
    __syncthreads();
#pragma unroll
    for (int kh2 = 0; kh2 < 2; ++kh2) {  // two K=32 halves of the BK=64 tile
      short8 af[4], bfr[4];
#pragma unroll
      for (int m = 0; m < 4; ++m)
        af[m] = *(const short8*)&Alds[(wr * 64 + m * 16 + lr) * 64 +
                                      ((((kh2 << 2) | lq) ^ (lr & 7)) << 3)];
#pragma unroll
      for (int n = 0; n < 4; ++n)
        bfr[n] = *(const short8*)&Blds[(wc * 64 + n * 16 + lr) * 64 +
                                       ((((kh2 << 2) | lq) ^ (lr & 7)) << 3)];
#pragma unroll
      for (int m = 0; m < 4; ++m)
#pragma unroll
        for (int n = 0; n < 4; ++n)
          acc[m][n] = __builtin_amdgcn_mfma_f32_16x16x32_bf16(af[m], bfr[n], acc[m][n], 0, 0, 0);
    }
    __syncthreads();
  }

#pragma unroll
  for (int m = 0; m < 4; ++m) {
#pragma unroll
    for (int n = 0; n < 4; ++n) {
      const int col = bn * 128 + wc * 64 + n * 16 + lr;
      const int s = col >> 9, h = (col >> 6) & 7, d = col & 63;
      const float bv = bias[h * 192 + d * 3 + s];
      const int hd = col & 511;
#pragma unroll
      for (int j = 0; j < 4; ++j) {
        const int row = bm * 128 + wr * 64 + m * 16 + lq * 4 + j;
        const float v = acc[m][n][j] + bv;
        if (s == 0)
          Qb[(size_t)row * 512 + hd] = __float2bfloat16(v * QSCALE);
        else if (s == 1)
          Kb[(size_t)row * 512 + hd] = __float2bfloat16(v);
        else
          Vt[((size_t)((row >> 11) * 8 + h) * 64 + d) * 2048 + (row & 2047)] =
              __float2bfloat16(v);
      }
    }
  }
}

// ------------- proj GEMM: 128x64 tile, BK=64, XOR-swizzled LDS -------------
// grid (64,8) = 512 blocks = 2 blocks/CU (fixes the 1-wave/SIMD latency wall).
__global__ __launch_bounds__(256, 2) void gemm_proj(const bf16* __restrict__ A,
                                                    const bf16* __restrict__ Bt,
                                                    const float* __restrict__ bias,
                                                    float* __restrict__ Cout) {
  __shared__ short Alds[128 * 64];  // 16 KB
  __shared__ short Blds[64 * 64];   // 8 KB
  const int t = threadIdx.x;
  const int w = t >> 6;
  const int wr = w >> 1, wc = w & 1;
  const int lr = t & 15;
  const int lq = (t >> 4) & 3;
  const int bm = blockIdx.x, bn = blockIdx.y;

  f32x4 acc[4][2];
#pragma unroll
  for (int m = 0; m < 4; ++m)
#pragma unroll
    for (int n = 0; n < 2; ++n)
#pragma unroll
      for (int j = 0; j < 4; ++j) acc[m][n][j] = 0.f;

  for (int kt = 0; kt < 8; ++kt) {
#pragma unroll
    for (int i = 0; i < 4; ++i) {
      const int c = i * 256 + t, r = c >> 3, g = (c & 7) ^ (r & 7);
      gload_lds16(A + (size_t)(bm * 128 + r) * 512 + kt * 64 + g * 8,
                  &Alds[(i * 256 + w * 64) * 8]);
    }
#pragma unroll
    for (int i = 0; i < 2; ++i) {
      const int c = i * 256 + t, r = c >> 3, g = (c & 7) ^ (r & 7);
      gload_lds16(Bt + (size_t)(bn * 64 + r) * 512 + kt * 64 + g * 8,
                  &Blds[(i * 256 + w * 64) * 8]);
    }
    __syncthreads();
#pragma unroll
    for (int kh2 = 0; kh2 < 2; ++kh2) {
      short8 af[4], bfr[2];
#pragma unroll
      for (int m = 0; m < 4; ++m)
        af[m] = *(const short8*)&Alds[(wr * 64 + m * 16 + lr) * 64 +
                                      ((((kh2 << 2) | lq) ^ (lr & 7)) << 3)];
#pragma unroll
      for (int n = 0; n < 2; ++n)
        bfr[n] = *(const short8*)&Blds[(wc * 32 + n * 16 + lr) * 64 +
                                       ((((kh2 << 2) | lq) ^ (lr & 7)) << 3)];
#pragma unroll
      for (int m = 0; m < 4; ++m)
#pragma unroll
        for (int n = 0; n < 2; ++n)
          acc[m][n] = __builtin_amdgcn_mfma_f32_16x16x32_bf16(af[m], bfr[n], acc[m][n], 0, 0, 0);
    }
    __syncthreads();
  }

#pragma unroll
  for (int m = 0; m < 4; ++m) {
#pragma unroll
    for (int n = 0; n < 2; ++n) {
      const int col = bn * 64 + wc * 32 + n * 16 + lr;
      const float bv = bias[col];
#pragma unroll
      for (int j = 0; j < 4; ++j) {
        const int row = bm * 128 + wr * 64 + m * 16 + lq * 4 + j;
        Cout[(size_t)row * 512 + col] = acc[m][n][j] + bv;
      }
    }
  }
}

// ---- flash attention fwd: 4 waves/block, key-split wave pairs, SHARED staging ----
// (unchanged: 2 waves/SIMD, exact split-K merge, no max-shift)
__global__ __launch_bounds__(256, 2) void attn_fwd(const bf16* __restrict__ Q,
                                                   const bf16* __restrict__ K,
                                                   const bf16* __restrict__ Vt,
                                                   bf16* __restrict__ O) {
  // [row 64][8 chunks of 16B], source-pre-swizzled: slot (r,cc) holds chunk cc^(r&7)
  __shared__ short Klds[2][64 * 64];  // [kv][d]   16 KB
  __shared__ short Vlds[2][64 * 64];  // [d][kv]   16 KB
  __shared__ float dnm[2][128];       // partial softmax denominators
  const int t = threadIdx.x;
  const int w = t >> 6;
  const int qw = w & 1;   // q-subtile
  const int kh = w >> 1;  // key-substep
  const int l = t & 63;
  const int lo = l & 31;
  const int hi = l >> 5;
  const int bid = blockIdx.x;
  const int bh = bid & 31, qt = bid >> 5;
  const int b = bh >> 3, h = bh & 7;
  const int qgA = qt * 128 + qw * 64 + lo;  // q-group A rows; B = A + 32

  const bf16* Kb = K + (size_t)b * 2048 * 512 + h * 64;
  const bf16* Vb = Vt + (size_t)bh * 64 * 2048;

  // Q fragments (B-operand of QK^T): lane -> Q[q][d = kk*16 + hi*8 + 0..7]
  const bf16* qptrA = Q + ((size_t)b * 2048 + qgA) * 512 + h * 64 + hi * 8;
  short8 qfA[4], qfB[4];
#pragma unroll
  for (int kk = 0; kk < 4; ++kk) {
    qfA[kk] = *(const short8*)(qptrA + kk * 16);
    qfB[kk] = *(const short8*)(qptrA + 32 * 512 + kk * 16);
  }

  // all-ones bf16 A-operand for row-sum MFMA
  union { unsigned u[4]; short8 v; } ones;
#pragma unroll
  for (int j = 0; j < 4; ++j) ones.u[j] = 0x3F803F80u;

  // persistent zero vector: C-operand of first QK^T MFMA (kills 32 v_mov per QK)
  f32x16 zv;
#pragma unroll
  for (int r = 0; r < 16; ++r) zv[r] = 0.f;

  f32x16 accA0, accA1, accB0, accB1;  // partial O^T: [d = crow(r,hi) + 32*dt][q]
  f32x16 ssumA, ssumB;                // partial P row-sums (every reg = lsum for q=lo)
#pragma unroll
  for (int r = 0; r < 16; ++r) {
    accA0[r] = 0.f; accA1[r] = 0.f; accB0[r] = 0.f; accB1[r] = 0.f;
    ssumA[r] = 0.f; ssumB[r] = 0.f;
  }

  // staging: 512 chunks each of K,V per tile; 256 threads -> 2 chunks each per array.
#define STAGE(BUF, KV0)                                                              \
  do {                                                                               \
    _Pragma("unroll") for (int i = 0; i < 2; ++i) {                                  \
      const int c = i * 256 + t, r = c >> 3, g = (c & 7) ^ (r & 7);                  \
      gload_lds16(Kb + (size_t)((KV0) + r) * 512 + g * 8,                            \
                  &Klds[BUF][(i * 256 + w * 64) * 8]);                               \
    }                                                                                \
    _Pragma("unroll") for (int i = 0; i < 2; ++i) {                                  \
      const int c = i * 256 + t, r = c >> 3, g = (c & 7) ^ (r & 7);                  \
      gload_lds16(Vb + (size_t)r * 2048 + (KV0) + g * 8,                             \
                  &Vlds[BUF][(i * 256 + w * 64) * 8]);                               \
    }                                                                                \
  } while (0)

  STAGE(0, 0);
  __syncthreads();

#pragma unroll 2
  for (int it = 0; it < 32; ++it) {
    const int buf = it & 1;
    if (it + 1 < 32) STAGE(buf ^ 1, (it + 1) * 64);

    const char* kl = (const char*)&Klds[buf][0];
    const char* vl = (const char*)&Vlds[buf][0];

    // K fragments for THIS wave's substep (rows kh*32+lo); (row&7) == (lo&7)
    short8 kf[4];
#pragma unroll
    for (int kk = 0; kk < 4; ++kk)
      kf[kk] = *(const short8*)(kl + ((kh * 32 + lo) << 7) +
                                ((((kk << 1) | hi) ^ (lo & 7)) << 4));

    // S^T = mfma(K, Q) for both q-groups; lane holds S[q=lo][k=crow(r,hi)]
    f32x16 sA, sB;
    __builtin_amdgcn_s_setprio(1);
#pragma unroll
    for (int kk = 0; kk < 4; ++kk) {
      sA = __builtin_amdgcn_mfma_f32_32x32x16_bf16(kf[kk], qfA[kk], kk ? sA : zv, 0, 0, 0);
      sB = __builtin_amdgcn_mfma_f32_32x32x16_bf16(kf[kk], qfB[kk], kk ? sB : zv, 0, 0, 0);
    }
    __builtin_amdgcn_s_setprio(0);

    // V^T fragments for this substep (independent of softmax; hides under QK)
    short8 vf[2][2];
#pragma unroll
    for (int dt = 0; dt < 2; ++dt)
#pragma unroll
      for (int j = 0; j < 2; ++j)
        vf[dt][j] = *(const short8*)(vl + ((dt * 32 + lo) << 7) +
                                     (((((kh * 2 + j) << 1) | hi) ^ (lo & 7)) << 4));

    // softmax numerator p = exp2(s) (scale folded into Q), single v_exp_f32 each
#pragma unroll
    for (int r = 0; r < 16; ++r) sA[r] = __builtin_amdgcn_exp2f(sA[r]);
#pragma unroll
    for (int r = 0; r < 16; ++r) sB[r] = __builtin_amdgcn_exp2f(sB[r]);
    short8 pbA[2], pbB[2];
    packP(sA, pbA);
    packP(sB, pbB);

    // partial O^T += V^T * P^T;  partial ssum += 1 * P^T
    __builtin_amdgcn_s_setprio(1);
#pragma unroll
    for (int j = 0; j < 2; ++j) {
      accA0 = __builtin_amdgcn_mfma_f32_32x32x16_bf16(vf[0][j], pbA[j], accA0, 0, 0, 0);
      accA1 = __builtin_amdgcn_mfma_f32_32x32x16_bf16(vf[1][j], pbA[j], accA1, 0, 0, 0);
      accB0 = __builtin_amdgcn_mfma_f32_32x32x16_bf16(vf[0][j], pbB[j], accB0, 0, 0, 0);
      accB1 = __builtin_amdgcn_mfma_f32_32x32x16_bf16(vf[1][j], pbB[j], accB1, 0, 0, 0);
      ssumA = __builtin_amdgcn_mfma_f32_32x32x16_bf16(ones.v, pbA[j], ssumA, 0, 0, 0);
      ssumB = __builtin_amdgcn_mfma_f32_32x32x16_bf16(ones.v, pbB[j], ssumB, 0, 0, 0);
    }
    __builtin_amdgcn_s_setprio(0);

    __syncthreads();  // drains vmcnt (next tile staged) + protects buffer reuse
  }
#undef STAGE

  // ---- split-K merge: kh=1 waves hand partials to kh=0 waves via LDS (exact add) ----
  float lsA = ssumA[0], lsB = ssumB[0];
  float* base = qw ? (float*)&Vlds[0][0] : (float*)&Klds[0][0];  // 16 KB per q-subtile
  if (kh) {
#pragma unroll
    for (int r = 0; r < 16; ++r) {  // rotate-indexed: bank = (r+l)%32, conflict-free
      base[l * 64 + ((r + l) & 63)] = accA0[r];
      base[l * 64 + ((16 + r + l) & 63)] = accA1[r];
      base[l * 64 + ((32 + r + l) & 63)] = accB0[r];
      base[l * 64 + ((48 + r + l) & 63)] = accB1[r];
    }
    dnm[qw][l] = lsA;
    dnm[qw][64 + l] = lsB;
  }
  __syncthreads();
  if (!kh) {
#pragma unroll
    for (int r = 0; r < 16; ++r) {
      accA0[r] += base[l * 64 + ((r + l) & 63)];
      accA1[r] += base[l * 64 + ((16 + r + l) & 63)];
      accB0[r] += base[l * 64 + ((32 + r + l) & 63)];
      accB1[r] += base[l * 64 + ((48 + r + l) & 63)];
    }
    lsA += dnm[qw][l];
    lsB += dnm[qw][64 + l];
    const float rlA = 1.0f / lsA;
    const float rlB = 1.0f / lsB;
    bf16* opA = O + ((size_t)b * 2048 + qgA) * 512 + h * 64;
    bf16* opB = opA + 32 * 512;
#pragma unroll
    for (int r = 0; r < 16; ++r) {
      const int d = (r & 3) + 8 * (r >> 2) + 4 * hi;
      opA[d] = __float2bfloat16(accA0[r] * rlA);
      opA[32 + d] = __float2bfloat16(accA1[r] * rlA);
      opB[d] = __float2bfloat16(accB0[r] * rlB);
      opB[32 + d] = __float2bfloat16(accB1[r] * rlB);
    }
  }
}

// ---------------- launch ----------------
extern "C" void kernel_launch(void* const* d_in, const int* in_sizes, int n_in,
                              void* d_out, int out_size, void* d_ws, size_t ws_size,
                              hipStream_t stream) {
  const float* x = (const float*)d_in[0];      // [4,2048,512]
  const float* Wqkv = (const float*)d_in[1];   // [512,1536]
  const float* bqkv = (const float*)d_in[2];   // [1536]
  const float* Wproj = (const float*)d_in[3];  // [512,512]
  const float* bproj = (const float*)d_in[4];  // [512]
  float* out = (float*)d_out;                  // [4,2048,512] fp32

  char* ws = (char*)d_ws;
  bf16* xb = (bf16*)ws;                       // 8192*512
  bf16* Wqkvt = xb + (size_t)8192 * 512;      // 1536*512
  bf16* Wprojt = Wqkvt + (size_t)1536 * 512;  // 512*512
  bf16* Qb = Wprojt + (size_t)512 * 512;      // 8192*512
  bf16* Kb = Qb + (size_t)8192 * 512;         // 8192*512
  bf16* Vt = Kb + (size_t)8192 * 512;         // 32*64*2048
  bf16* Ob = xb;                              // alias: xb dead after gemm_qkv

  prep_kernel<<<2304, 256, 0, stream>>>(x, xb, Wqkv, Wqkvt, Wproj, Wprojt);
  gemm_qkv<<<dim3(64, 12), 256, 0, stream>>>(xb, Wqkvt, bqkv, Qb, Kb, Vt);
  attn_fwd<<<512, 256, 0, stream>>>(Qb, Kb, Vt, Ob);
  gemm_proj<<<dim3(64, 8), 256, 0, stream>>>(Ob, Wprojt, bproj, out);
}

// Round 11
// 92.975 us; speedup vs baseline: 1.1982x; 1.0186x over previous
//
#include <hip/hip_runtime.h>
#include <hip/hip_bf16.h>

typedef __hip_bfloat16 bf16;
typedef __attribute__((ext_vector_type(8))) short short8;
typedef __attribute__((ext_vector_type(4))) float f32x4;
typedef __attribute__((ext_vector_type(16))) float f32x16;

// exp2-domain Q scale: log2(e) / sqrt(512)  (reference divides energies by sqrt(E))
static constexpr float QSCALE = 1.4426950408889634f / 22.627416997969522f;

__device__ __forceinline__ void gload_lds16(const void* g, void* l) {
  __builtin_amdgcn_global_load_lds((const __attribute__((address_space(1))) unsigned*)(g),
                                   (__attribute__((address_space(3))) unsigned*)(l), 16, 0, 0);
}

// one v_cvt_pk_bf16_f32: {lo16=bf16(a), hi16=bf16(b)} (T12 recipe, m214v22)
__device__ __forceinline__ unsigned cvtpk(float a, float b) {
  unsigned r;
  asm("v_cvt_pk_bf16_f32 %0, %1, %2" : "=v"(r) : "v"(a), "v"(b));
  return r;
}

// pack a 32-wide P row-slice (f32x16, this lane's 16 + partner's 16) into two
// B-operand bf16 fragments via cvt_pk + permlane32_swap (one swap fills 2 words)
__device__ __forceinline__ void packP(const f32x16& s, short8* pb) {
#pragma unroll
  for (int g = 0; g < 2; ++g) {
    unsigned a0 = cvtpk(s[8 * g + 0], s[8 * g + 1]);
    unsigned a1 = cvtpk(s[8 * g + 2], s[8 * g + 3]);
    unsigned b0 = cvtpk(s[8 * g + 4], s[8 * g + 5]);
    unsigned b1 = cvtpk(s[8 * g + 6], s[8 * g + 7]);
    asm("v_permlane32_swap_b32 %0, %1" : "+v"(a0), "+v"(b0));
    asm("v_permlane32_swap_b32 %0, %1" : "+v"(a1), "+v"(b1));
    union { unsigned u[4]; short8 v; } pu;
    pu.u[0] = a0; pu.u[1] = a1; pu.u[2] = b0; pu.u[3] = b1;
    pb[g] = pu.v;
  }
}

// ------ fused prep: cvt x->bf16 (blocks 0..2047), Wqkv transpose+permute (2048..2239),
// ------ Wproj transpose (2240..2303). Branch is block-uniform -> __syncthreads legal.
__global__ __launch_bounds__(256) void prep_kernel(const float* __restrict__ x,
                                                   bf16* __restrict__ xb,
                                                   const float* __restrict__ Wqkv,
                                                   bf16* __restrict__ Wqkvt,
                                                   const float* __restrict__ Wproj,
                                                   bf16* __restrict__ Wprojt) {
  __shared__ float tile[64][65];
  const int bid = blockIdx.x;
  if (bid < 2048) {
    // ---- cvt_x: 8 elems/thread, one pass ----
    const int i = bid * 256 + threadIdx.x;  // 0..524287 = 8192*512/8
    const float4* src = (const float4*)(x) + (size_t)i * 2;
    float4 a = src[0], b = src[1];
    union { short8 v; unsigned u[4]; } o;
    o.u[0] = cvtpk(a.x, a.y);
    o.u[1] = cvtpk(a.z, a.w);
    o.u[2] = cvtpk(b.x, b.y);
    o.u[3] = cvtpk(b.z, b.w);
    *(short8*)(xb + (size_t)i * 8) = o.v;
  } else {
    // ---- weight transpose+cvt: Wt[j'][k] = W[k][j] ----
    const float* W;
    bf16* Wt;
    int Nout, permute, j0, k0;
    if (bid < 2048 + 192) {
      const int tb = bid - 2048;  // 24 x 8 tiles
      W = Wqkv; Wt = Wqkvt; Nout = 1536; permute = 1;
      j0 = (tb % 24) * 64; k0 = (tb / 24) * 64;
    } else {
      const int tb = bid - 2240;  // 8 x 8 tiles
      W = Wproj; Wt = Wprojt; Nout = 512; permute = 0;
      j0 = (tb % 8) * 64; k0 = (tb / 8) * 64;
    }
    const int tx = threadIdx.x & 63, ty = threadIdx.x >> 6;
    for (int r = ty; r < 64; r += 4)
      tile[r][tx] = W[(size_t)(k0 + r) * Nout + j0 + tx];
    __syncthreads();
    for (int r = ty; r < 64; r += 4) {
      int j = j0 + r;
      int jp = j;
      if (permute) {
        int h = j / 192, rr = j % 192, d = rr / 3, s = rr % 3;
        jp = s * 512 + h * 64 + d;
      }
      Wt[(size_t)jp * 512 + k0 + tx] = __float2bfloat16(tile[tx][r]);
    }
  }
}

// ------------- QKV GEMM: 128x128 tile, BK=64, XOR-swizzled LDS (T2) -------------
// A [8192][512] bf16; Bt [1536][512] bf16 (out-col-major). Epilogue scatters to
// Q (pre-scaled), K, and V^T with the (h,d,s) de-interleave + bias.
__global__ __launch_bounds__(256, 3) void gemm_qkv(const bf16* __restrict__ A,
                                                   const bf16* __restrict__ Bt,
                                                   const float* __restrict__ bias,
                                                   bf16* __restrict__ Qb,
                                                   bf16* __restrict__ Kb,
                                                   bf16* __restrict__ Vt) {
  __shared__ short Alds[128 * 64];  // [row][8 chunks of 16B], chunk slot cc holds src chunk cc^(row&7)
  __shared__ short Blds[128 * 64];
  const int t = threadIdx.x;
  const int w = t >> 6;
  const int wr = w >> 1, wc = w & 1;
  const int lr = t & 15;
  const int lq = (t >> 4) & 3;
  const int bm = blockIdx.x, bn = blockIdx.y;

  f32x4 acc[4][4];
#pragma unroll
  for (int m = 0; m < 4; ++m)
#pragma unroll
    for (int n = 0; n < 4; ++n)
#pragma unroll
      for (int j = 0; j < 4; ++j) acc[m][n][j] = 0.f;

  for (int kt = 0; kt < 8; ++kt) {
    // stage 128x64 A and B tiles: 1024 chunks each, 4/thread, source-pre-swizzled
#pragma unroll
    for (int i = 0; i < 4; ++i) {
      const int c = i * 256 + t, r = c >> 3, g = (c & 7) ^ (r & 7);
      gload_lds16(A + (size_t)(bm * 128 + r) * 512 + kt * 64 + g * 8,
                  &Alds[(i * 256 + w * 64) * 8]);
    }
#pragma unroll
    for (int i = 0; i < 4; ++i) {
      const int c = i * 256 + t, r = c >> 3, g = (c & 7) ^ (r & 7);
      gload_lds16(Bt + (size_t)(bn * 128 + r) * 512 + kt * 64 + g * 8,
                  &Blds[(i * 256 + w * 64) * 8]);
    }
    __syncthreads();
#pragma unroll
    for (int kh2 = 0; kh2 < 2; ++kh2) {  // two K=32 halves of the BK=64 tile
      short8 af[4], bfr[4];
#pragma unroll
      for (int m = 0; m < 4; ++m)
        af[m] = *(const short8*)&Alds[(wr * 64 + m * 16 + lr) * 64 +
                                      ((((kh2 << 2) | lq) ^ (lr & 7)) << 3)];
#pragma unroll
      for (int n = 0; n < 4; ++n)
        bfr[n] = *(const short8*)&Blds[(wc * 64 + n * 16 + lr) * 64 +
                                       ((((kh2 << 2) | lq) ^ (lr & 7)) << 3)];
#pragma unroll
      for (int m = 0; m < 4; ++m)
#pragma unroll
        for (int n = 0; n < 4; ++n)
          acc[m][n] = __builtin_amdgcn_mfma_f32_16x16x32_bf16(af[m], bfr[n], acc[m][n], 0, 0, 0);
    }
    __syncthreads();
  }

#pragma unroll
  for (int m = 0; m < 4; ++m) {
#pragma unroll
    for (int n = 0; n < 4; ++n) {
      const int col = bn * 128 + wc * 64 + n * 16 + lr;
      const int s = col >> 9, h = (col >> 6) & 7, d = col & 63;
      const float bv = bias[h * 192 + d * 3 + s];
      const int hd = col & 511;
#pragma unroll
      for (int j = 0; j < 4; ++j) {
        const int row = bm * 128 + wr * 64 + m * 16 + lq * 4 + j;
        const float v = acc[m][n][j] + bv;
        if (s == 0)
          Qb[(size_t)row * 512 + hd] = __float2bfloat16(v * QSCALE);
        else if (s == 1)
          Kb[(size_t)row * 512 + hd] = __float2bfloat16(v);
        else
          Vt[((size_t)((row >> 11) * 8 + h) * 64 + d) * 2048 + (row & 2047)] =
              __float2bfloat16(v);
      }
    }
  }
}

// ------------- proj GEMM: 128x64 tile, BK=64, XOR-swizzled LDS -------------
// grid (64,8) = 512 blocks = 2 blocks/CU (fixes the 1-wave/SIMD latency wall).
__global__ __launch_bounds__(256, 2) void gemm_proj(const bf16* __restrict__ A,
                                                    const bf16* __restrict__ Bt,
                                                    const float* __restrict__ bias,
                                                    float* __restrict__ Cout) {
  __shared__ short Alds[128 * 64];  // 16 KB
  __shared__ short Blds[64 * 64];   // 8 KB
  const int t = threadIdx.x;
  const int w = t >> 6;
  const int wr = w >> 1, wc = w & 1;
  const int lr = t & 15;
  const int lq = (t >> 4) & 3;
  const int bm = blockIdx.x, bn = blockIdx.y;

  f32x4 acc[4][2];
#pragma unroll
  for (int m = 0; m < 4; ++m)
#pragma unroll
    for (int n = 0; n < 2; ++n)
#pragma unroll
      for (int j = 0; j < 4; ++j) acc[m][n][j] = 0.f;

  for (int kt = 0; kt < 8; ++kt) {
#pragma unroll
    for (int i = 0; i < 4; ++i) {
      const int c = i * 256 + t, r = c >> 3, g = (c & 7) ^ (r & 7);
      gload_lds16(A + (size_t)(bm * 128 + r) * 512 + kt * 64 + g * 8,
                  &Alds[(i * 256 + w * 64) * 8]);
    }
#pragma unroll
    for (int i = 0; i < 2; ++i) {
      const int c = i * 256 + t, r = c >> 3, g = (c & 7) ^ (r & 7);
      gload_lds16(Bt + (size_t)(bn * 64 + r) * 512 + kt * 64 + g * 8,
                  &Blds[(i * 256 + w * 64) * 8]);
    }
    __syncthreads();
#pragma unroll
    for (int kh2 = 0; kh2 < 2; ++kh2) {
      short8 af[4], bfr[2];
#pragma unroll
      for (int m = 0; m < 4; ++m)
        af[m] = *(const short8*)&Alds[(wr * 64 + m * 16 + lr) * 64 +
                                      ((((kh2 << 2) | lq) ^ (lr & 7)) << 3)];
#pragma unroll
      for (int n = 0; n < 2; ++n)
        bfr[n] = *(const short8*)&Blds[(wc * 32 + n * 16 + lr) * 64 +
                                       ((((kh2 << 2) | lq) ^ (lr & 7)) << 3)];
#pragma unroll
      for (int m = 0; m < 4; ++m)
#pragma unroll
        for (int n = 0; n < 2; ++n)
          acc[m][n] = __builtin_amdgcn_mfma_f32_16x16x32_bf16(af[m], bfr[n], acc[m][n], 0, 0, 0);
    }
    __syncthreads();
  }

#pragma unroll
  for (int m = 0; m < 4; ++m) {
#pragma unroll
    for (int n = 0; n < 2; ++n) {
      const int col = bn * 64 + wc * 32 + n * 16 + lr;
      const float bv = bias[col];
#pragma unroll
      for (int j = 0; j < 4; ++j) {
        const int row = bm * 128 + wr * 64 + m * 16 + lq * 4 + j;
        Cout[(size_t)row * 512 + col] = acc[m][n][j] + bv;
      }
    }
  }
}

// ---- flash attention fwd: 4 waves/block, key-split wave pairs, KVBLK=128 ----
// Same structure as round 8-10 (2 waves/SIMD, exact split-K merge, no max-shift)
// but 128-key staged tiles: 16 iterations instead of 32 -> half the barrier-pair
// overhead; per-CU totals (staging bytes, ds_reads, MFMA, VALU) unchanged.
// K tile [128 kv][64 d] (rows 128B, XOR involution r&7); V tile [64 d][128 kv]
// (rows 256B, XOR involution r&15 over 16 chunks -> vf lanes hit 16 banks x2 = free).
__global__ __launch_bounds__(256, 2) void attn_fwd(const bf16* __restrict__ Q,
                                                   const bf16* __restrict__ K,
                                                   const bf16* __restrict__ Vt,
                                                   bf16* __restrict__ O) {
  __shared__ short Klds[2][128 * 64];  // [kv][d]  16 KB/buf
  __shared__ short Vlds[2][64 * 128];  // [d][kv]  16 KB/buf
  __shared__ float dnm[2][128];        // partial softmax denominators
  const int t = threadIdx.x;
  const int w = t >> 6;
  const int qw = w & 1;   // q-subtile
  const int kh = w >> 1;  // key-half of each 128-key tile
  const int l = t & 63;
  const int lo = l & 31;
  const int hi = l >> 5;
  const int bid = blockIdx.x;
  const int bh = bid & 31, qt = bid >> 5;
  const int b = bh >> 3, h = bh & 7;
  const int qgA = qt * 128 + qw * 64 + lo;  // q-group A rows; B = A + 32

  const bf16* Kb = K + (size_t)b * 2048 * 512 + h * 64;
  const bf16* Vb = Vt + (size_t)bh * 64 * 2048;

  // Q fragments (B-operand of QK^T): lane -> Q[q][d = kk*16 + hi*8 + 0..7]
  const bf16* qptrA = Q + ((size_t)b * 2048 + qgA) * 512 + h * 64 + hi * 8;
  short8 qfA[4], qfB[4];
#pragma unroll
  for (int kk = 0; kk < 4; ++kk) {
    qfA[kk] = *(const short8*)(qptrA + kk * 16);
    qfB[kk] = *(const short8*)(qptrA + 32 * 512 + kk * 16);
  }

  // all-ones bf16 A-operand for row-sum MFMA
  union { unsigned u[4]; short8 v; } ones;
#pragma unroll
  for (int j = 0; j < 4; ++j) ones.u[j] = 0x3F803F80u;

  // persistent zero vector: C-operand of first QK^T MFMA (kills 32 v_mov per QK)
  f32x16 zv;
#pragma unroll
  for (int r = 0; r < 16; ++r) zv[r] = 0.f;

  f32x16 accA0, accA1, accB0, accB1;  // partial O^T: [d = crow(r,hi) + 32*dt][q]
  f32x16 ssumA, ssumB;                // partial P row-sums (every reg = lsum for q=lo)
#pragma unroll
  for (int r = 0; r < 16; ++r) {
    accA0[r] = 0.f; accA1[r] = 0.f; accB0[r] = 0.f; accB1[r] = 0.f;
    ssumA[r] = 0.f; ssumB[r] = 0.f;
  }

  // staging (128-key tile): K = 1024 chunks (128 rows x 8), V = 1024 chunks
  // (64 rows x 16); 256 threads -> 4 chunks each per array, source-pre-swizzled.
#define STAGE(BUF, KV0)                                                              \
  do {                                                                               \
    _Pragma("unroll") for (int i = 0; i < 4; ++i) {                                  \
      const int c = i * 256 + t, r = c >> 3, g = (c & 7) ^ (r & 7);                  \
      gload_lds16(Kb + (size_t)((KV0) + r) * 512 + g * 8,                            \
                  &Klds[BUF][(i * 256 + w * 64) * 8]);                               \
    }                                                                                \
    _Pragma("unroll") for (int i = 0; i < 4; ++i) {                                  \
      const int c = i * 256 + t, r = c >> 4, g = (c & 15) ^ (r & 15);                \
      gload_lds16(Vb + (size_t)r * 2048 + (KV0) + g * 8,                             \
                  &Vlds[BUF][(i * 256 + w * 64) * 8]);                               \
    }                                                                                \
  } while (0)

  STAGE(0, 0);
  __syncthreads();

#pragma unroll 2
  for (int it = 0; it < 16; ++it) {
    const int buf = it & 1;
    if (it + 1 < 16) STAGE(buf ^ 1, (it + 1) * 128);

    const char* kl = (const char*)&Klds[buf][0];
    const char* vl = (const char*)&Vlds[buf][0];

#pragma unroll
    for (int sh = 0; sh < 2; ++sh) {  // 32-key substep: keys it*128 + kh*64 + sh*32 + lo
      // K fragments: row kh*64 + sh*32 + lo (row&7 == lo&7)
      short8 kf[4];
#pragma unroll
      for (int kk = 0; kk < 4; ++kk)
        kf[kk] = *(const short8*)(kl + ((kh * 64 + sh * 32 + lo) << 7) +
                                  ((((kk << 1) | hi) ^ (lo & 7)) << 4));

      // S^T = mfma(K, Q) for both q-groups; lane holds S[q=lo][k=crow(r,hi)]
      f32x16 sA, sB;
      __builtin_amdgcn_s_setprio(1);
#pragma unroll
      for (int kk = 0; kk < 4; ++kk) {
        sA = __builtin_amdgcn_mfma_f32_32x32x16_bf16(kf[kk], qfA[kk], kk ? sA : zv, 0, 0, 0);
        sB = __builtin_amdgcn_mfma_f32_32x32x16_bf16(kf[kk], qfB[kk], kk ? sB : zv, 0, 0, 0);
      }
      __builtin_amdgcn_s_setprio(0);

      // V^T fragments: row dt*32+lo (256B rows), chunk (kh*8+sh*4+j*2+hi)^(lo&15)
      short8 vf[2][2];
#pragma unroll
      for (int dt = 0; dt < 2; ++dt)
#pragma unroll
        for (int j = 0; j < 2; ++j)
          vf[dt][j] = *(const short8*)(vl + ((dt * 32 + lo) << 8) +
                                       ((((kh << 3) | (sh << 2) | (j << 1) | hi) ^ (lo & 15))
                                        << 4));

      // softmax numerator p = exp2(s) (scale folded into Q), single v_exp_f32 each
#pragma unroll
      for (int r = 0; r < 16; ++r) sA[r] = __builtin_amdgcn_exp2f(sA[r]);
#pragma unroll
      for (int r = 0; r < 16; ++r) sB[r] = __builtin_amdgcn_exp2f(sB[r]);
      short8 pbA[2], pbB[2];
      packP(sA, pbA);
      packP(sB, pbB);

      // partial O^T += V^T * P^T;  partial ssum += 1 * P^T
      __builtin_amdgcn_s_setprio(1);
#pragma unroll
      for (int j = 0; j < 2; ++j) {
        accA0 = __builtin_amdgcn_mfma_f32_32x32x16_bf16(vf[0][j], pbA[j], accA0, 0, 0, 0);
        accA1 = __builtin_amdgcn_mfma_f32_32x32x16_bf16(vf[1][j], pbA[j], accA1, 0, 0, 0);
        accB0 = __builtin_amdgcn_mfma_f32_32x32x16_bf16(vf[0][j], pbB[j], accB0, 0, 0, 0);
        accB1 = __builtin_amdgcn_mfma_f32_32x32x16_bf16(vf[1][j], pbB[j], accB1, 0, 0, 0);
        ssumA = __builtin_amdgcn_mfma_f32_32x32x16_bf16(ones.v, pbA[j], ssumA, 0, 0, 0);
        ssumB = __builtin_amdgcn_mfma_f32_32x32x16_bf16(ones.v, pbB[j], ssumB, 0, 0, 0);
      }
      __builtin_amdgcn_s_setprio(0);
    }

    __syncthreads();  // drains vmcnt (next tile staged) + protects buffer reuse
  }
#undef STAGE

  // ---- split-K merge: kh=1 waves hand partials to kh=0 waves via LDS (exact add) ----
  float lsA = ssumA[0], lsB = ssumB[0];
  float* base = qw ? (float*)&Vlds[0][0] : (float*)&Klds[0][0];  // 16 KB per q-subtile
  if (kh) {
#pragma unroll
    for (int r = 0; r < 16; ++r) {  // rotate-indexed: bank = (r+l)%32, conflict-free
      base[l * 64 + ((r + l) & 63)] = accA0[r];
      base[l * 64 + ((16 + r + l) & 63)] = accA1[r];
      base[l * 64 + ((32 + r + l) & 63)] = accB0[r];
      base[l * 64 + ((48 + r + l) & 63)] = accB1[r];
    }
    dnm[qw][l] = lsA;
    dnm[qw][64 + l] = lsB;
  }
  __syncthreads();
  if (!kh) {
#pragma unroll
    for (int r = 0; r < 16; ++r) {
      accA0[r] += base[l * 64 + ((r + l) & 63)];
      accA1[r] += base[l * 64 + ((16 + r + l) & 63)];
      accB0[r] += base[l * 64 + ((32 + r + l) & 63)];
      accB1[r] += base[l * 64 + ((48 + r + l) & 63)];
    }
    lsA += dnm[qw][l];
    lsB += dnm[qw][64 + l];
    const float rlA = 1.0f / lsA;
    const float rlB = 1.0f / lsB;
    bf16* opA = O + ((size_t)b * 2048 + qgA) * 512 + h * 64;
    bf16* opB = opA + 32 * 512;
#pragma unroll
    for (int r = 0; r < 16; ++r) {
      const int d = (r & 3) + 8 * (r >> 2) + 4 * hi;
      opA[d] = __float2bfloat16(accA0[r] * rlA);
      opA[32 + d] = __float2bfloat16(accA1[r] * rlA);
      opB[d] = __float2bfloat16(accB0[r] * rlB);
      opB[32 + d] = __float2bfloat16(accB1[r] * rlB);
    }
  }
}

// ---------------- launch ----------------
extern "C" void kernel_launch(void* const* d_in, const int* in_sizes, int n_in,
                              void* d_out, int out_size, void* d_ws, size_t ws_size,
                              hipStream_t stream) {
  const float* x = (const float*)d_in[0];      // [4,2048,512]
  const float* Wqkv = (const float*)d_in[1];   // [512,1536]
  const float* bqkv = (const float*)d_in[2];   // [1536]
  const float* Wproj = (const float*)d_in[3];  // [512,512]
  const float* bproj = (const float*)d_in[4];  // [512]
  float* out = (float*)d_out;                  // [4,2048,512] fp32

  char* ws = (char*)d_ws;
  bf16* xb = (bf16*)ws;                       // 8192*512
  bf16* Wqkvt = xb + (size_t)8192 * 512;      // 1536*512
  bf16* Wprojt = Wqkvt + (size_t)1536 * 512;  // 512*512
  bf16* Qb = Wprojt + (size_t)512 * 512;      // 8192*512
  bf16* Kb = Qb + (size_t)8192 * 512;         // 8192*512
  bf16* Vt = Kb + (size_t)8192 * 512;         // 32*64*2048
  bf16* Ob = xb;                              // alias: xb dead after gemm_qkv

  prep_kernel<<<2304, 256, 0, stream>>>(x, xb, Wqkv, Wqkvt, Wproj, Wprojt);
  gemm_qkv<<<dim3(64, 12), 256, 0, stream>>>(xb, Wqkvt, bqkv, Qb, Kb, Vt);
  attn_fwd<<<512, 256, 0, stream>>>(Qb, Kb, Vt, Ob);
  gemm_proj<<<dim3(64, 8), 256, 0, stream>>>(Ob, Wprojt, bproj, out);
}